// Round 1
// baseline (1298.355 us; speedup 1.0000x reference)
//
#include <hip/hip_runtime.h>

#define TLEN 24
#define HID 32
#define NNODES 10000

__device__ __forceinline__ float sigmoidf_(float v) { return 1.f / (1.f + __expf(-v)); }
__device__ __forceinline__ float tanhf_(float v) { float e = __expf(2.f * v); return 1.f - 2.f / (e + 1.f); }

// ---------------- GRU (one thread per sequence) + fused xw1 = h @ W1 ----------------
__global__ __launch_bounds__(256) void gru_xw1_kernel(
    const float* __restrict__ x, const float* __restrict__ w_ih,
    const float* __restrict__ w_hh, const float* __restrict__ b_ih,
    const float* __restrict__ b_hh, const float* __restrict__ W1,
    float* __restrict__ xw1, int BN)
{
    int m = blockIdx.x * 256 + threadIdx.x;
    if (m >= BN) return;
    const float* xr = x + (size_t)m * TLEN;

    float h[HID];
#pragma unroll
    for (int i = 0; i < HID; i++) h[i] = 0.f;
    float r[HID], z[HID];

#pragma unroll 1
    for (int t = 0; t < TLEN; t++) {
        float xt = xr[t];
        // r gate (rows 0..31)
#pragma unroll
        for (int g = 0; g < HID; g++) {
            float a = b_hh[g];
#pragma unroll
            for (int j = 0; j < HID; j++) a = fmaf(h[j], w_hh[g * HID + j], a);
            float pre = fmaf(xt, w_ih[g], b_ih[g]) + a;
            r[g] = sigmoidf_(pre);
        }
        // z gate (rows 32..63)
#pragma unroll
        for (int g = 0; g < HID; g++) {
            float a = b_hh[HID + g];
#pragma unroll
            for (int j = 0; j < HID; j++) a = fmaf(h[j], w_hh[(HID + g) * HID + j], a);
            float pre = fmaf(xt, w_ih[HID + g], b_ih[HID + g]) + a;
            z[g] = sigmoidf_(pre);
        }
        // n gate (rows 64..95): pre = xn + r * (dot + b_hh); reuse r[] to store n
#pragma unroll
        for (int g = 0; g < HID; g++) {
            float a = b_hh[2 * HID + g];
#pragma unroll
            for (int j = 0; j < HID; j++) a = fmaf(h[j], w_hh[(2 * HID + g) * HID + j], a);
            float pre = fmaf(xt, w_ih[2 * HID + g], b_ih[2 * HID + g]) + r[g] * a;
            r[g] = tanhf_(pre);
        }
#pragma unroll
        for (int g = 0; g < HID; g++) h[g] = (1.f - z[g]) * r[g] + z[g] * h[g];
    }

    // epilogue: xw1 = h @ W1   (W1 stored [in=32, out=32])
    float4* op = reinterpret_cast<float4*>(xw1 + (size_t)m * HID);
#pragma unroll
    for (int oc = 0; oc < 8; oc++) {
        float tmp[4];
#pragma unroll
        for (int u = 0; u < 4; u++) {
            int o = oc * 4 + u;
            float a = 0.f;
#pragma unroll
            for (int j = 0; j < HID; j++) a = fmaf(h[j], W1[j * HID + o], a);
            tmp[u] = a;
        }
        float4 v; v.x = tmp[0]; v.y = tmp[1]; v.z = tmp[2]; v.w = tmp[3];
        op[oc] = v;
    }
}

// ---------------- graph prep: degree, dinv, CSR over tgt ----------------
__global__ void init_deg_cnt(float* deg, int* cnt, int N)
{
    int i = blockIdx.x * 256 + threadIdx.x;
    if (i < N) { deg[i] = 1.0f; cnt[i] = 1; }  // self-loop weight 1, one slot
}

__global__ void deg_accum(const int* __restrict__ src, const int* __restrict__ tgt,
                          const float* __restrict__ ew, float* deg, int* cnt, int E)
{
    int e = blockIdx.x * 256 + threadIdx.x;
    if (e < E) {
        int t = tgt[e];
        atomicAdd(&deg[t], ew[e]);
        atomicAdd(&cnt[t], 1);
    }
}

__global__ void dinv_kernel(const float* __restrict__ deg, float* dinv, int N)
{
    int i = blockIdx.x * 256 + threadIdx.x;
    if (i < N) {
        float d = deg[i];
        dinv[i] = d > 0.f ? rsqrtf(d) : 0.f;
    }
}

// single-block exclusive scan of cnt -> offs[N+1]; cursor[i] = offs[i]
__global__ void scan_kernel(const int* __restrict__ cnt, int* offs, int* cursor, int N)
{
    __shared__ int sdata[1024];
    __shared__ int carry;
    int tid = threadIdx.x;
    if (tid == 0) { carry = 0; offs[0] = 0; }
    __syncthreads();
    for (int base = 0; base < N; base += 1024) {
        int i = base + tid;
        int v = (i < N) ? cnt[i] : 0;
        sdata[tid] = v;
        __syncthreads();
        int acc = v;
        for (int ofs = 1; ofs < 1024; ofs <<= 1) {
            int y = (tid >= ofs) ? sdata[tid - ofs] : 0;
            __syncthreads();
            acc += y;
            sdata[tid] = acc;
            __syncthreads();
        }
        if (i < N) {
            offs[i + 1] = carry + acc;
            cursor[i] = carry + acc - v;
        }
        __syncthreads();
        if (tid == 1023) carry += sdata[1023];
        __syncthreads();
    }
}

__global__ void fill_csr(const int* __restrict__ src, const int* __restrict__ tgt,
                         const float* __restrict__ ew, const float* __restrict__ dinv,
                         int* cursor, int* csr_src, float* csr_norm, int E, int N)
{
    int i = blockIdx.x * 256 + threadIdx.x;
    if (i < E) {
        int s = src[i], t = tgt[i];
        int pos = atomicAdd(&cursor[t], 1);
        csr_src[pos] = s;
        csr_norm[pos] = dinv[s] * ew[i] * dinv[t];
    } else if (i < E + N) {
        int n = i - E;
        int pos = atomicAdd(&cursor[n], 1);
        csr_src[pos] = n;
        csr_norm[pos] = dinv[n] * dinv[n];
    }
}

// ---------------- conv1: h1 = relu(gather-sum(xw1) + b1) ----------------
// wave = (node, batch-pair); lane = feature(32) x batch-half(2)
__global__ __launch_bounds__(256) void conv1_kernel(
    const float* __restrict__ xw1, const int* __restrict__ offs,
    const int* __restrict__ csrc, const float* __restrict__ cnorm,
    const float* __restrict__ b1, float* __restrict__ h1, int N)
{
    int wave = (blockIdx.x << 2) + (threadIdx.x >> 6);
    int lane = threadIdx.x & 63;
    int n = __builtin_amdgcn_readfirstlane(wave >> 3);
    int p = wave & 7;
    int f = lane & 31;
    int b = (p << 1) + (lane >> 5);
    int beg = __builtin_amdgcn_readfirstlane(offs[n]);
    int end = __builtin_amdgcn_readfirstlane(offs[n + 1]);
    int rowbase = b * N;
    float acc = 0.f;
    for (int i = beg; i < end; i++) {
        int s = csrc[i];
        float wn = cnorm[i];
        acc = fmaf(wn, xw1[((rowbase + s) << 5) + f], acc);
    }
    float v = acc + b1[f];
    h1[((rowbase + n) << 5) + f] = fmaxf(v, 0.f);
}

// ---------------- xw2 = h1 @ W2 (W2 stored [32,16]) ----------------
__global__ __launch_bounds__(256) void xw2_kernel(
    const float* __restrict__ h1, const float* __restrict__ W2,
    float* __restrict__ xw2, int BN)
{
    int m = blockIdx.x * 256 + threadIdx.x;
    if (m >= BN) return;
    float hin[32];
    const float4* hp = reinterpret_cast<const float4*>(h1 + (size_t)m * 32);
#pragma unroll
    for (int i = 0; i < 8; i++) {
        float4 v = hp[i];
        hin[4 * i] = v.x; hin[4 * i + 1] = v.y; hin[4 * i + 2] = v.z; hin[4 * i + 3] = v.w;
    }
    float4* op = reinterpret_cast<float4*>(xw2 + (size_t)m * 16);
#pragma unroll
    for (int oc = 0; oc < 4; oc++) {
        float tmp[4];
#pragma unroll
        for (int u = 0; u < 4; u++) {
            int o = oc * 4 + u;
            float a = 0.f;
#pragma unroll
            for (int j = 0; j < 32; j++) a = fmaf(hin[j], W2[j * 16 + o], a);
            tmp[u] = a;
        }
        float4 v; v.x = tmp[0]; v.y = tmp[1]; v.z = tmp[2]; v.w = tmp[3];
        op[oc] = v;
    }
}

// ---------------- conv2 + final linear: out = (gather-sum(xw2)+b2) @ Wfc + bfc ----------------
// wave = (node, batch-quad); lane = feature(16) x batch(4)
__global__ __launch_bounds__(256) void conv2_kernel(
    const float* __restrict__ xw2, const int* __restrict__ offs,
    const int* __restrict__ csrc, const float* __restrict__ cnorm,
    const float* __restrict__ b2, const float* __restrict__ Wfc,
    const float* __restrict__ bfc, float* __restrict__ out, int N)
{
    int wave = (blockIdx.x << 2) + (threadIdx.x >> 6);
    int lane = threadIdx.x & 63;
    int n = __builtin_amdgcn_readfirstlane(wave >> 2);
    int q = wave & 3;
    int f = lane & 15;
    int b = (q << 2) + (lane >> 4);
    int beg = __builtin_amdgcn_readfirstlane(offs[n]);
    int end = __builtin_amdgcn_readfirstlane(offs[n + 1]);
    float acc = 0.f;
    for (int i = beg; i < end; i++) {
        int s = csrc[i];
        float wn = cnorm[i];
        acc = fmaf(wn, xw2[((b * N + s) << 4) + f], acc);
    }
    float h2 = acc + b2[f];
    float prod = h2 * Wfc[f];
#pragma unroll
    for (int o = 1; o < 16; o <<= 1) prod += __shfl_xor(prod, o, 16);
    if (f == 0) out[b * N + n] = prod + bfc[0];
}

extern "C" void kernel_launch(void* const* d_in, const int* in_sizes, int n_in,
                              void* d_out, int out_size, void* d_ws, size_t ws_size,
                              hipStream_t stream)
{
    const float* x    = (const float*)d_in[0];
    const int*   eidx = (const int*)d_in[1];
    const float* ew   = (const float*)d_in[2];
    const float* w_ih = (const float*)d_in[3];
    const float* w_hh = (const float*)d_in[4];
    const float* b_ih = (const float*)d_in[5];
    const float* b_hh = (const float*)d_in[6];
    const float* W1   = (const float*)d_in[7];
    const float* b1   = (const float*)d_in[8];
    const float* W2   = (const float*)d_in[9];
    const float* b2   = (const float*)d_in[10];
    const float* Wfc  = (const float*)d_in[11];
    const float* bfc  = (const float*)d_in[12];

    const int E  = in_sizes[2];
    const int BN = in_sizes[0] / TLEN;   // 160000
    const int N  = NNODES;               // 10000
    const int* esrc = eidx;
    const int* etgt = eidx + E;
    float* out = (float*)d_out;

    // workspace carve (≈53 MB)
    char* w = (char*)d_ws;
    auto alloc = [&](size_t bytes) -> char* {
        char* p = w;
        w += (bytes + 255) / 256 * 256;
        return p;
    };
    float* xw1      = (float*)alloc((size_t)BN * 32 * 4);
    float* h1       = (float*)alloc((size_t)BN * 32 * 4);
    float* xw2      = (float*)alloc((size_t)BN * 16 * 4);
    float* deg      = (float*)alloc((size_t)N * 4);
    float* dinv     = (float*)alloc((size_t)N * 4);
    int*   cnt      = (int*)alloc((size_t)N * 4);
    int*   offs     = (int*)alloc((size_t)(N + 4) * 4);
    int*   cursor   = (int*)alloc((size_t)N * 4);
    int*   csr_src  = (int*)alloc((size_t)(E + N) * 4);
    float* csr_norm = (float*)alloc((size_t)(E + N) * 4);

    hipLaunchKernelGGL(init_deg_cnt, dim3((N + 255) / 256), dim3(256), 0, stream, deg, cnt, N);
    hipLaunchKernelGGL(deg_accum, dim3((E + 255) / 256), dim3(256), 0, stream, esrc, etgt, ew, deg, cnt, E);
    hipLaunchKernelGGL(dinv_kernel, dim3((N + 255) / 256), dim3(256), 0, stream, deg, dinv, N);
    hipLaunchKernelGGL(scan_kernel, dim3(1), dim3(1024), 0, stream, cnt, offs, cursor, N);
    hipLaunchKernelGGL(fill_csr, dim3((E + N + 255) / 256), dim3(256), 0, stream,
                       esrc, etgt, ew, dinv, cursor, csr_src, csr_norm, E, N);

    hipLaunchKernelGGL(gru_xw1_kernel, dim3((BN + 255) / 256), dim3(256), 0, stream,
                       x, w_ih, w_hh, b_ih, b_hh, W1, xw1, BN);
    hipLaunchKernelGGL(conv1_kernel, dim3(N * 2), dim3(256), 0, stream,
                       xw1, offs, csr_src, csr_norm, b1, h1, N);
    hipLaunchKernelGGL(xw2_kernel, dim3((BN + 255) / 256), dim3(256), 0, stream, h1, W2, xw2, BN);
    hipLaunchKernelGGL(conv2_kernel, dim3(N), dim3(256), 0, stream,
                       xw2, offs, csr_src, csr_norm, b2, Wfc, bfc, out, N);
}

// Round 2
// 1066.553 us; speedup vs baseline: 1.2173x; 1.2173x over previous
//
#include <hip/hip_runtime.h>

#define TLEN 24
#define HID 32
#define NNODES 10000

__device__ __forceinline__ float sigmoidf_(float v) { return 1.f / (1.f + __expf(-v)); }
__device__ __forceinline__ float tanhf_(float v) { float e = __expf(2.f * v); return 1.f - 2.f / (e + 1.f); }

// ---------------- GRU, lane-parallel over hidden dim ----------------
// lane g = tid&31 owns gate rows g (r,z,n) in registers; 2 seqs per wave.
// h[j] broadcast via __shfl (ds_bpermute). Fused epilogue xw1 = h @ W1.
__global__ __launch_bounds__(256, 2) void gru_xw1_kernel(
    const float* __restrict__ x, const float* __restrict__ w_ih,
    const float* __restrict__ w_hh, const float* __restrict__ b_ih,
    const float* __restrict__ b_hh, const float* __restrict__ W1,
    float* __restrict__ xw1, int BN)
{
    const int tid = threadIdx.x;
    const int g = tid & 31;
    int seq = blockIdx.x * 8 + (tid >> 5);
    if (seq >= BN) seq = BN - 1;  // duplicate work, identical value written
    const int base = tid & 32;    // shuffle base: own half of the wave

    // --- per-lane weights in registers (loaded once; whole-wave reads are
    // per-j single cache lines for W1, 128B-strided rows for w_hh) ---
    float wr[32], wz[32], wn[32], wc[32];
#pragma unroll
    for (int u = 0; u < 8; u++) {
        float4 v = *reinterpret_cast<const float4*>(&w_hh[g * 32 + u * 4]);
        wr[u * 4 + 0] = v.x; wr[u * 4 + 1] = v.y; wr[u * 4 + 2] = v.z; wr[u * 4 + 3] = v.w;
    }
#pragma unroll
    for (int u = 0; u < 8; u++) {
        float4 v = *reinterpret_cast<const float4*>(&w_hh[(32 + g) * 32 + u * 4]);
        wz[u * 4 + 0] = v.x; wz[u * 4 + 1] = v.y; wz[u * 4 + 2] = v.z; wz[u * 4 + 3] = v.w;
    }
#pragma unroll
    for (int u = 0; u < 8; u++) {
        float4 v = *reinterpret_cast<const float4*>(&w_hh[(64 + g) * 32 + u * 4]);
        wn[u * 4 + 0] = v.x; wn[u * 4 + 1] = v.y; wn[u * 4 + 2] = v.z; wn[u * 4 + 3] = v.w;
    }
#pragma unroll
    for (int j = 0; j < 32; j++) wc[j] = W1[j * 32 + g];   // W1 column g

    const float u_r = w_ih[g], u_z = w_ih[32 + g], u_n = w_ih[64 + g];
    const float pre_r = b_ih[g] + b_hh[g];
    const float pre_z = b_ih[32 + g] + b_hh[32 + g];
    const float bin_n = b_ih[64 + g];
    const float bhn_n = b_hh[64 + g];

    const float* xr = x + (size_t)seq * TLEN;
    float xt = xr[0];
    float h = 0.f;

#pragma unroll 1
    for (int t = 0; t < TLEN; t++) {
        float xnext = (t < TLEN - 1) ? xr[t + 1] : 0.f;  // prefetch next step
        float ar = 0.f, az = 0.f, an = 0.f;
#pragma unroll
        for (int j = 0; j < 32; j++) {
            float hj = __shfl(h, base + j);
            ar = fmaf(hj, wr[j], ar);
            az = fmaf(hj, wz[j], az);
            an = fmaf(hj, wn[j], an);
        }
        float r = sigmoidf_(fmaf(xt, u_r, pre_r) + ar);
        float z = sigmoidf_(fmaf(xt, u_z, pre_z) + az);
        float n = tanhf_(fmaf(xt, u_n, bin_n) + r * (an + bhn_n));
        h = n + z * (h - n);
        xt = xnext;
    }

    // epilogue: xw1[seq][g] = sum_j h[j] * W1[j][g]
    float acc = 0.f;
#pragma unroll
    for (int j = 0; j < 32; j++) {
        float hj = __shfl(h, base + j);
        acc = fmaf(hj, wc[j], acc);
    }
    xw1[(size_t)seq * HID + g] = acc;
}

// ---------------- graph prep: degree, dinv, CSR over tgt ----------------
__global__ void init_deg_cnt(float* deg, int* cnt, int N)
{
    int i = blockIdx.x * 256 + threadIdx.x;
    if (i < N) { deg[i] = 1.0f; cnt[i] = 1; }  // self-loop weight 1, one slot
}

__global__ void deg_accum(const int* __restrict__ src, const int* __restrict__ tgt,
                          const float* __restrict__ ew, float* deg, int* cnt, int E)
{
    int e = blockIdx.x * 256 + threadIdx.x;
    if (e < E) {
        int t = tgt[e];
        atomicAdd(&deg[t], ew[e]);
        atomicAdd(&cnt[t], 1);
    }
}

__global__ void dinv_kernel(const float* __restrict__ deg, float* dinv, int N)
{
    int i = blockIdx.x * 256 + threadIdx.x;
    if (i < N) {
        float d = deg[i];
        dinv[i] = d > 0.f ? rsqrtf(d) : 0.f;
    }
}

// single-block exclusive scan of cnt -> offs[N+1]; cursor[i] = offs[i]
__global__ void scan_kernel(const int* __restrict__ cnt, int* offs, int* cursor, int N)
{
    __shared__ int sdata[1024];
    __shared__ int carry;
    int tid = threadIdx.x;
    if (tid == 0) { carry = 0; offs[0] = 0; }
    __syncthreads();
    for (int base = 0; base < N; base += 1024) {
        int i = base + tid;
        int v = (i < N) ? cnt[i] : 0;
        sdata[tid] = v;
        __syncthreads();
        int acc = v;
        for (int ofs = 1; ofs < 1024; ofs <<= 1) {
            int y = (tid >= ofs) ? sdata[tid - ofs] : 0;
            __syncthreads();
            acc += y;
            sdata[tid] = acc;
            __syncthreads();
        }
        if (i < N) {
            offs[i + 1] = carry + acc;
            cursor[i] = carry + acc - v;
        }
        __syncthreads();
        if (tid == 1023) carry += sdata[1023];
        __syncthreads();
    }
}

__global__ void fill_csr(const int* __restrict__ src, const int* __restrict__ tgt,
                         const float* __restrict__ ew, const float* __restrict__ dinv,
                         int* cursor, int* csr_src, float* csr_norm, int E, int N)
{
    int i = blockIdx.x * 256 + threadIdx.x;
    if (i < E) {
        int s = src[i], t = tgt[i];
        int pos = atomicAdd(&cursor[t], 1);
        csr_src[pos] = s;
        csr_norm[pos] = dinv[s] * ew[i] * dinv[t];
    } else if (i < E + N) {
        int n = i - E;
        int pos = atomicAdd(&cursor[n], 1);
        csr_src[pos] = n;
        csr_norm[pos] = dinv[n] * dinv[n];
    }
}

// ---------------- conv1: h1 = relu(gather-sum(xw1) + b1) ----------------
__global__ __launch_bounds__(256) void conv1_kernel(
    const float* __restrict__ xw1, const int* __restrict__ offs,
    const int* __restrict__ csrc, const float* __restrict__ cnorm,
    const float* __restrict__ b1, float* __restrict__ h1, int N)
{
    int wave = (blockIdx.x << 2) + (threadIdx.x >> 6);
    int lane = threadIdx.x & 63;
    int n = __builtin_amdgcn_readfirstlane(wave >> 3);
    int p = wave & 7;
    int f = lane & 31;
    int b = (p << 1) + (lane >> 5);
    int beg = __builtin_amdgcn_readfirstlane(offs[n]);
    int end = __builtin_amdgcn_readfirstlane(offs[n + 1]);
    int rowbase = b * N;
    float acc = 0.f;
    for (int i = beg; i < end; i++) {
        int s = csrc[i];
        float wn = cnorm[i];
        acc = fmaf(wn, xw1[((rowbase + s) << 5) + f], acc);
    }
    float v = acc + b1[f];
    h1[((rowbase + n) << 5) + f] = fmaxf(v, 0.f);
}

// ---------------- xw2 = h1 @ W2 (W2 stored [32,16]) ----------------
__global__ __launch_bounds__(256) void xw2_kernel(
    const float* __restrict__ h1, const float* __restrict__ W2,
    float* __restrict__ xw2, int BN)
{
    int m = blockIdx.x * 256 + threadIdx.x;
    if (m >= BN) return;
    float hin[32];
    const float4* hp = reinterpret_cast<const float4*>(h1 + (size_t)m * 32);
#pragma unroll
    for (int i = 0; i < 8; i++) {
        float4 v = hp[i];
        hin[4 * i] = v.x; hin[4 * i + 1] = v.y; hin[4 * i + 2] = v.z; hin[4 * i + 3] = v.w;
    }
    float4* op = reinterpret_cast<float4*>(xw2 + (size_t)m * 16);
#pragma unroll
    for (int oc = 0; oc < 4; oc++) {
        float tmp[4];
#pragma unroll
        for (int u = 0; u < 4; u++) {
            int o = oc * 4 + u;
            float a = 0.f;
#pragma unroll
            for (int j = 0; j < 32; j++) a = fmaf(hin[j], W2[j * 16 + o], a);
            tmp[u] = a;
        }
        float4 v; v.x = tmp[0]; v.y = tmp[1]; v.z = tmp[2]; v.w = tmp[3];
        op[oc] = v;
    }
}

// ---------------- conv2 + final linear ----------------
__global__ __launch_bounds__(256) void conv2_kernel(
    const float* __restrict__ xw2, const int* __restrict__ offs,
    const int* __restrict__ csrc, const float* __restrict__ cnorm,
    const float* __restrict__ b2, const float* __restrict__ Wfc,
    const float* __restrict__ bfc, float* __restrict__ out, int N)
{
    int wave = (blockIdx.x << 2) + (threadIdx.x >> 6);
    int lane = threadIdx.x & 63;
    int n = __builtin_amdgcn_readfirstlane(wave >> 2);
    int q = wave & 3;
    int f = lane & 15;
    int b = (q << 2) + (lane >> 4);
    int beg = __builtin_amdgcn_readfirstlane(offs[n]);
    int end = __builtin_amdgcn_readfirstlane(offs[n + 1]);
    float acc = 0.f;
    for (int i = beg; i < end; i++) {
        int s = csrc[i];
        float wn = cnorm[i];
        acc = fmaf(wn, xw2[((b * N + s) << 4) + f], acc);
    }
    float h2 = acc + b2[f];
    float prod = h2 * Wfc[f];
#pragma unroll
    for (int o = 1; o < 16; o <<= 1) prod += __shfl_xor(prod, o, 16);
    if (f == 0) out[b * N + n] = prod + bfc[0];
}

extern "C" void kernel_launch(void* const* d_in, const int* in_sizes, int n_in,
                              void* d_out, int out_size, void* d_ws, size_t ws_size,
                              hipStream_t stream)
{
    const float* x    = (const float*)d_in[0];
    const int*   eidx = (const int*)d_in[1];
    const float* ew   = (const float*)d_in[2];
    const float* w_ih = (const float*)d_in[3];
    const float* w_hh = (const float*)d_in[4];
    const float* b_ih = (const float*)d_in[5];
    const float* b_hh = (const float*)d_in[6];
    const float* W1   = (const float*)d_in[7];
    const float* b1   = (const float*)d_in[8];
    const float* W2   = (const float*)d_in[9];
    const float* b2   = (const float*)d_in[10];
    const float* Wfc  = (const float*)d_in[11];
    const float* bfc  = (const float*)d_in[12];

    const int E  = in_sizes[2];
    const int BN = in_sizes[0] / TLEN;   // 160000
    const int N  = NNODES;               // 10000
    const int* esrc = eidx;
    const int* etgt = eidx + E;
    float* out = (float*)d_out;

    char* w = (char*)d_ws;
    auto alloc = [&](size_t bytes) -> char* {
        char* p = w;
        w += (bytes + 255) / 256 * 256;
        return p;
    };
    float* xw1      = (float*)alloc((size_t)BN * 32 * 4);
    float* h1       = (float*)alloc((size_t)BN * 32 * 4);
    float* xw2      = (float*)alloc((size_t)BN * 16 * 4);
    float* deg      = (float*)alloc((size_t)N * 4);
    float* dinv     = (float*)alloc((size_t)N * 4);
    int*   cnt      = (int*)alloc((size_t)N * 4);
    int*   offs     = (int*)alloc((size_t)(N + 4) * 4);
    int*   cursor   = (int*)alloc((size_t)N * 4);
    int*   csr_src  = (int*)alloc((size_t)(E + N) * 4);
    float* csr_norm = (float*)alloc((size_t)(E + N) * 4);

    hipLaunchKernelGGL(init_deg_cnt, dim3((N + 255) / 256), dim3(256), 0, stream, deg, cnt, N);
    hipLaunchKernelGGL(deg_accum, dim3((E + 255) / 256), dim3(256), 0, stream, esrc, etgt, ew, deg, cnt, E);
    hipLaunchKernelGGL(dinv_kernel, dim3((N + 255) / 256), dim3(256), 0, stream, deg, dinv, N);
    hipLaunchKernelGGL(scan_kernel, dim3(1), dim3(1024), 0, stream, cnt, offs, cursor, N);
    hipLaunchKernelGGL(fill_csr, dim3((E + N + 255) / 256), dim3(256), 0, stream,
                       esrc, etgt, ew, dinv, cursor, csr_src, csr_norm, E, N);

    hipLaunchKernelGGL(gru_xw1_kernel, dim3((BN + 7) / 8), dim3(256), 0, stream,
                       x, w_ih, w_hh, b_ih, b_hh, W1, xw1, BN);
    hipLaunchKernelGGL(conv1_kernel, dim3(N * 2), dim3(256), 0, stream,
                       xw1, offs, csr_src, csr_norm, b1, h1, N);
    hipLaunchKernelGGL(xw2_kernel, dim3((BN + 255) / 256), dim3(256), 0, stream, h1, W2, xw2, BN);
    hipLaunchKernelGGL(conv2_kernel, dim3(N), dim3(256), 0, stream,
                       xw2, offs, csr_src, csr_norm, b2, Wfc, bfc, out, N);
}

// Round 3
// 760.282 us; speedup vs baseline: 1.7077x; 1.4028x over previous
//
#include <hip/hip_runtime.h>

#define TLEN 24
#define HID 32
#define NNODES 10000

typedef __attribute__((ext_vector_type(4))) float f4;

__device__ __forceinline__ float sigmoidf_(float v) { return 1.f / (1.f + __expf(-v)); }
__device__ __forceinline__ float tanhf_(float v) { float e = __expf(2.f * v); return 1.f - 2.f / (e + 1.f); }

// ---------------- GRU, lane-parallel over hidden dim ----------------
// lane g = lane&31 owns gate rows g (r,z,n); 2 seqs per wave (half = lane>>5).
// Weights pinned in VGPRs via inline-asm; h broadcast via LDS write + 8x
// broadcast ds_read_b128 per step. Fused epilogue xw1 = h @ W1.
__global__ __launch_bounds__(256, 2) void gru_xw1_kernel(
    const float* __restrict__ x, const float* __restrict__ w_ih,
    const float* __restrict__ w_hh, const float* __restrict__ b_ih,
    const float* __restrict__ b_hh, const float* __restrict__ W1,
    float* __restrict__ xw1, int BN)
{
    __shared__ float hbuf[4][64];
    __shared__ float xbuf[4][48];
    const int tid = threadIdx.x;
    const int wv = tid >> 6, lane = tid & 63, g = lane & 31, half = lane >> 5;
    int seq = blockIdx.x * 8 + wv * 2 + half;
    if (seq >= BN) seq = BN - 1;  // duplicate work, identical value written

    // --- per-lane weights in registers, pinned ---
    f4 wr[8], wz[8], wn[8];
    const f4* whr = reinterpret_cast<const f4*>(w_hh + g * 32);
    const f4* whz = reinterpret_cast<const f4*>(w_hh + (32 + g) * 32);
    const f4* whn = reinterpret_cast<const f4*>(w_hh + (64 + g) * 32);
#pragma unroll
    for (int u = 0; u < 8; u++) { wr[u] = whr[u]; wz[u] = whz[u]; wn[u] = whn[u]; }
    asm volatile("" : "+v"(wr[0]), "+v"(wr[1]), "+v"(wr[2]), "+v"(wr[3]),
                      "+v"(wr[4]), "+v"(wr[5]), "+v"(wr[6]), "+v"(wr[7]));
    asm volatile("" : "+v"(wz[0]), "+v"(wz[1]), "+v"(wz[2]), "+v"(wz[3]),
                      "+v"(wz[4]), "+v"(wz[5]), "+v"(wz[6]), "+v"(wz[7]));
    asm volatile("" : "+v"(wn[0]), "+v"(wn[1]), "+v"(wn[2]), "+v"(wn[3]),
                      "+v"(wn[4]), "+v"(wn[5]), "+v"(wn[6]), "+v"(wn[7]));

    const float u_r = w_ih[g], u_z = w_ih[32 + g], u_n = w_ih[64 + g];
    const float pre_r = b_ih[g] + b_hh[g];
    const float pre_z = b_ih[32 + g] + b_hh[32 + g];
    const float bin_n = b_ih[64 + g];
    const float bhn_n = b_hh[64 + g];

    // stage this wave's x rows in LDS (broadcast-read per step, no VMEM in loop)
    if (g < TLEN) xbuf[wv][half * TLEN + g] = x[(size_t)seq * TLEN + g];

    float hv[32];
#pragma unroll
    for (int j = 0; j < 32; j++) hv[j] = 0.f;
    float hown = 0.f;

#pragma unroll 1
    for (int t = 0; t < TLEN; t++) {
        float xt = xbuf[wv][half * TLEN + t];
        float ar0 = 0.f, ar1 = 0.f, az0 = 0.f, az1 = 0.f, an0 = 0.f, an1 = 0.f;
#pragma unroll
        for (int j = 0; j < 16; j++) {
            ar0 = fmaf(hv[j],      wr[j >> 2][j & 3], ar0);
            az0 = fmaf(hv[j],      wz[j >> 2][j & 3], az0);
            an0 = fmaf(hv[j],      wn[j >> 2][j & 3], an0);
            ar1 = fmaf(hv[16 + j], wr[4 + (j >> 2)][j & 3], ar1);
            az1 = fmaf(hv[16 + j], wz[4 + (j >> 2)][j & 3], az1);
            an1 = fmaf(hv[16 + j], wn[4 + (j >> 2)][j & 3], an1);
        }
        float r = sigmoidf_(fmaf(xt, u_r, pre_r) + ar0 + ar1);
        float z = sigmoidf_(fmaf(xt, u_z, pre_z) + az0 + az1);
        float n = tanhf_(fmaf(xt, u_n, bin_n) + r * (an0 + an1 + bhn_n));
        hown = n + z * (hown - n);
        hbuf[wv][lane] = hown;
        // broadcast read-back: all 32 lanes of a half read identical addresses
        const f4* hp = reinterpret_cast<const f4*>(&hbuf[wv][half * 32]);
#pragma unroll
        for (int u = 0; u < 8; u++) {
            f4 v = hp[u];
            hv[u * 4 + 0] = v[0]; hv[u * 4 + 1] = v[1];
            hv[u * 4 + 2] = v[2]; hv[u * 4 + 3] = v[3];
        }
    }

    // epilogue: xw1[seq][g] = sum_j h[j] * W1[j][g]  (coalesced W1 row reads)
    float acc = 0.f;
#pragma unroll
    for (int j = 0; j < 32; j++) acc = fmaf(hv[j], W1[j * 32 + g], acc);
    xw1[(size_t)seq * HID + g] = acc;
}

// ---------------- graph prep: degree, dinv, CSR over tgt ----------------
__global__ void init_deg_cnt(float* deg, int* cnt, int N)
{
    int i = blockIdx.x * 256 + threadIdx.x;
    if (i < N) { deg[i] = 1.0f; cnt[i] = 1; }  // self-loop weight 1, one slot
}

__global__ void deg_accum(const int* __restrict__ src, const int* __restrict__ tgt,
                          const float* __restrict__ ew, float* deg, int* cnt, int E)
{
    int e = blockIdx.x * 256 + threadIdx.x;
    if (e < E) {
        int t = tgt[e];
        atomicAdd(&deg[t], ew[e]);
        atomicAdd(&cnt[t], 1);
    }
}

__global__ void dinv_kernel(const float* __restrict__ deg, float* dinv, int N)
{
    int i = blockIdx.x * 256 + threadIdx.x;
    if (i < N) {
        float d = deg[i];
        dinv[i] = d > 0.f ? rsqrtf(d) : 0.f;
    }
}

// single-block exclusive scan of cnt -> offs[N+1]; cursor[i] = offs[i]
__global__ void scan_kernel(const int* __restrict__ cnt, int* offs, int* cursor, int N)
{
    __shared__ int sdata[1024];
    __shared__ int carry;
    int tid = threadIdx.x;
    if (tid == 0) { carry = 0; offs[0] = 0; }
    __syncthreads();
    for (int base = 0; base < N; base += 1024) {
        int i = base + tid;
        int v = (i < N) ? cnt[i] : 0;
        sdata[tid] = v;
        __syncthreads();
        int acc = v;
        for (int ofs = 1; ofs < 1024; ofs <<= 1) {
            int y = (tid >= ofs) ? sdata[tid - ofs] : 0;
            __syncthreads();
            acc += y;
            sdata[tid] = acc;
            __syncthreads();
        }
        if (i < N) {
            offs[i + 1] = carry + acc;
            cursor[i] = carry + acc - v;
        }
        __syncthreads();
        if (tid == 1023) carry += sdata[1023];
        __syncthreads();
    }
}

__global__ void fill_csr(const int* __restrict__ src, const int* __restrict__ tgt,
                         const float* __restrict__ ew, const float* __restrict__ dinv,
                         int* cursor, int* csr_src, float* csr_norm, int E, int N)
{
    int i = blockIdx.x * 256 + threadIdx.x;
    if (i < E) {
        int s = src[i], t = tgt[i];
        int pos = atomicAdd(&cursor[t], 1);
        csr_src[pos] = s;
        csr_norm[pos] = dinv[s] * ew[i] * dinv[t];
    } else if (i < E + N) {
        int n = i - E;
        int pos = atomicAdd(&cursor[n], 1);
        csr_src[pos] = n;
        csr_norm[pos] = dinv[n] * dinv[n];
    }
}

// ---------------- conv1: h1 = relu(gather-sum(xw1) + b1) ----------------
__global__ __launch_bounds__(256) void conv1_kernel(
    const float* __restrict__ xw1, const int* __restrict__ offs,
    const int* __restrict__ csrc, const float* __restrict__ cnorm,
    const float* __restrict__ b1, float* __restrict__ h1, int N)
{
    int wave = (blockIdx.x << 2) + (threadIdx.x >> 6);
    int lane = threadIdx.x & 63;
    int n = __builtin_amdgcn_readfirstlane(wave >> 3);
    int p = wave & 7;
    int f = lane & 31;
    int b = (p << 1) + (lane >> 5);
    int beg = __builtin_amdgcn_readfirstlane(offs[n]);
    int end = __builtin_amdgcn_readfirstlane(offs[n + 1]);
    int rowbase = b * N;
    float acc = 0.f;
    for (int i = beg; i < end; i++) {
        int s = csrc[i];
        float wn = cnorm[i];
        acc = fmaf(wn, xw1[((rowbase + s) << 5) + f], acc);
    }
    float v = acc + b1[f];
    h1[((rowbase + n) << 5) + f] = fmaxf(v, 0.f);
}

// ---------------- xw2 = h1 @ W2 (W2 stored [32,16]) ----------------
__global__ __launch_bounds__(256) void xw2_kernel(
    const float* __restrict__ h1, const float* __restrict__ W2,
    float* __restrict__ xw2, int BN)
{
    int m = blockIdx.x * 256 + threadIdx.x;
    if (m >= BN) return;
    float hin[32];
    const float4* hp = reinterpret_cast<const float4*>(h1 + (size_t)m * 32);
#pragma unroll
    for (int i = 0; i < 8; i++) {
        float4 v = hp[i];
        hin[4 * i] = v.x; hin[4 * i + 1] = v.y; hin[4 * i + 2] = v.z; hin[4 * i + 3] = v.w;
    }
    float4* op = reinterpret_cast<float4*>(xw2 + (size_t)m * 16);
#pragma unroll
    for (int oc = 0; oc < 4; oc++) {
        float tmp[4];
#pragma unroll
        for (int u = 0; u < 4; u++) {
            int o = oc * 4 + u;
            float a = 0.f;
#pragma unroll
            for (int j = 0; j < 32; j++) a = fmaf(hin[j], W2[j * 16 + o], a);
            tmp[u] = a;
        }
        float4 v; v.x = tmp[0]; v.y = tmp[1]; v.z = tmp[2]; v.w = tmp[3];
        op[oc] = v;
    }
}

// ---------------- conv2 + final linear ----------------
__global__ __launch_bounds__(256) void conv2_kernel(
    const float* __restrict__ xw2, const int* __restrict__ offs,
    const int* __restrict__ csrc, const float* __restrict__ cnorm,
    const float* __restrict__ b2, const float* __restrict__ Wfc,
    const float* __restrict__ bfc, float* __restrict__ out, int N)
{
    int wave = (blockIdx.x << 2) + (threadIdx.x >> 6);
    int lane = threadIdx.x & 63;
    int n = __builtin_amdgcn_readfirstlane(wave >> 2);
    int q = wave & 3;
    int f = lane & 15;
    int b = (q << 2) + (lane >> 4);
    int beg = __builtin_amdgcn_readfirstlane(offs[n]);
    int end = __builtin_amdgcn_readfirstlane(offs[n + 1]);
    float acc = 0.f;
    for (int i = beg; i < end; i++) {
        int s = csrc[i];
        float wn = cnorm[i];
        acc = fmaf(wn, xw2[((b * N + s) << 4) + f], acc);
    }
    float h2 = acc + b2[f];
    float prod = h2 * Wfc[f];
#pragma unroll
    for (int o = 1; o < 16; o <<= 1) prod += __shfl_xor(prod, o, 16);
    if (f == 0) out[b * N + n] = prod + bfc[0];
}

extern "C" void kernel_launch(void* const* d_in, const int* in_sizes, int n_in,
                              void* d_out, int out_size, void* d_ws, size_t ws_size,
                              hipStream_t stream)
{
    const float* x    = (const float*)d_in[0];
    const int*   eidx = (const int*)d_in[1];
    const float* ew   = (const float*)d_in[2];
    const float* w_ih = (const float*)d_in[3];
    const float* w_hh = (const float*)d_in[4];
    const float* b_ih = (const float*)d_in[5];
    const float* b_hh = (const float*)d_in[6];
    const float* W1   = (const float*)d_in[7];
    const float* b1   = (const float*)d_in[8];
    const float* W2   = (const float*)d_in[9];
    const float* b2   = (const float*)d_in[10];
    const float* Wfc  = (const float*)d_in[11];
    const float* bfc  = (const float*)d_in[12];

    const int E  = in_sizes[2];
    const int BN = in_sizes[0] / TLEN;   // 160000
    const int N  = NNODES;               // 10000
    const int* esrc = eidx;
    const int* etgt = eidx + E;
    float* out = (float*)d_out;

    char* w = (char*)d_ws;
    auto alloc = [&](size_t bytes) -> char* {
        char* p = w;
        w += (bytes + 255) / 256 * 256;
        return p;
    };
    float* xw1      = (float*)alloc((size_t)BN * 32 * 4);
    float* h1       = (float*)alloc((size_t)BN * 32 * 4);
    float* xw2      = (float*)alloc((size_t)BN * 16 * 4);
    float* deg      = (float*)alloc((size_t)N * 4);
    float* dinv     = (float*)alloc((size_t)N * 4);
    int*   cnt      = (int*)alloc((size_t)N * 4);
    int*   offs     = (int*)alloc((size_t)(N + 4) * 4);
    int*   cursor   = (int*)alloc((size_t)N * 4);
    int*   csr_src  = (int*)alloc((size_t)(E + N) * 4);
    float* csr_norm = (float*)alloc((size_t)(E + N) * 4);

    hipLaunchKernelGGL(init_deg_cnt, dim3((N + 255) / 256), dim3(256), 0, stream, deg, cnt, N);
    hipLaunchKernelGGL(deg_accum, dim3((E + 255) / 256), dim3(256), 0, stream, esrc, etgt, ew, deg, cnt, E);
    hipLaunchKernelGGL(dinv_kernel, dim3((N + 255) / 256), dim3(256), 0, stream, deg, dinv, N);
    hipLaunchKernelGGL(scan_kernel, dim3(1), dim3(1024), 0, stream, cnt, offs, cursor, N);
    hipLaunchKernelGGL(fill_csr, dim3((E + N + 255) / 256), dim3(256), 0, stream,
                       esrc, etgt, ew, dinv, cursor, csr_src, csr_norm, E, N);

    hipLaunchKernelGGL(gru_xw1_kernel, dim3((BN + 7) / 8), dim3(256), 0, stream,
                       x, w_ih, w_hh, b_ih, b_hh, W1, xw1, BN);
    hipLaunchKernelGGL(conv1_kernel, dim3(N * 2), dim3(256), 0, stream,
                       xw1, offs, csr_src, csr_norm, b1, h1, N);
    hipLaunchKernelGGL(xw2_kernel, dim3((BN + 255) / 256), dim3(256), 0, stream, h1, W2, xw2, BN);
    hipLaunchKernelGGL(conv2_kernel, dim3(N), dim3(256), 0, stream,
                       xw2, offs, csr_src, csr_norm, b2, Wfc, bfc, out, N);
}

// Round 4
// 410.014 us; speedup vs baseline: 3.1666x; 1.8543x over previous
//
#include <hip/hip_runtime.h>

#define TLEN 24
#define HID 32
#define NNODES 10000

typedef __attribute__((ext_vector_type(8))) short short8;
typedef __attribute__((ext_vector_type(4))) float floatx4;

__device__ __forceinline__ unsigned short bf16_rne(float f) {
    unsigned u = __float_as_uint(f);
    unsigned r = u + 0x7fffu + ((u >> 16) & 1u);
    return (unsigned short)(r >> 16);
}
__device__ __forceinline__ float bf16_tof(unsigned short b) {
    return __uint_as_float(((unsigned)b) << 16);
}

#define MFMA16(a, b, c) __builtin_amdgcn_mfma_f32_16x16x32_bf16((a), (b), (c), 0, 0, 0)

// ---------------- GRU via MFMA, 16 seqs per wave ----------------
// D tiles: row rho (perm) = gate-row g = 8*(rho>>2)+(rho&3) (+4 odd tile).
// Lane l: u=l>>4, s=l&15. Lane's D regs hold g=8u+{0..7}, seq s -> B-frag
// for next step is in-lane (k = 8u+j). 18 MFMA/step + fused xw1 epilogue.
__global__ __launch_bounds__(256, 2) void gru_xw1_kernel(
    const float* __restrict__ x, const float* __restrict__ w_ih,
    const float* __restrict__ w_hh, const float* __restrict__ b_ih,
    const float* __restrict__ b_hh, const float* __restrict__ W1,
    float* __restrict__ xw1, int BN)
{
    __shared__ float xs[64][25];
    const int tid = threadIdx.x;
    const int wv = tid >> 6, lane = tid & 63;
    const int u = lane >> 4;      // k-chunk and own-g chunk
    const int s = lane & 15;      // seq within tile / A-row index

    // stage x for the block's 64 seqs
    for (int i = tid; i < 64 * TLEN; i += 256) {
        int sl = i / TLEN, t = i - sl * TLEN;
        int gseq = blockIdx.x * 64 + sl;
        if (gseq >= BN) gseq = BN - 1;
        xs[sl][t] = x[(size_t)gseq * TLEN + t];
    }
    __syncthreads();

    // ---- load w_hh A-fragments (hi/lo), permuted rows ----
    const int arow_g = 8 * (s >> 2) + (s & 3);
    short8 wh[6], wl[6];
#pragma unroll
    for (int G = 0; G < 3; G++) {
#pragma unroll
        for (int hf = 0; hf < 2; hf++) {
            int row = G * 32 + arow_g + 4 * hf;
            const float* wp = w_hh + row * 32 + 8 * u;
            short8 a, b;
#pragma unroll
            for (int j = 0; j < 8; j++) {
                float wfull = wp[j];
                unsigned short hb = bf16_rne(wfull);
                float lo = wfull - bf16_tof(hb);
                a[j] = (short)hb;
                b[j] = (short)bf16_rne(lo);
            }
            wh[G * 2 + hf] = a;
            wl[G * 2 + hf] = b;
        }
    }

    // per-lane gate constants for own g-set: g = 8u + i
    float u_r[8], u_z[8], u_n[8], pr[8], pz[8], bni[8], bnh[8];
#pragma unroll
    for (int i = 0; i < 8; i++) {
        int g = 8 * u + i;
        u_r[i] = w_ih[g]; u_z[i] = w_ih[32 + g]; u_n[i] = w_ih[64 + g];
        pr[i] = b_ih[g] + b_hh[g];
        pz[i] = b_ih[32 + g] + b_hh[32 + g];
        bni[i] = b_ih[64 + g];
        bnh[i] = b_hh[64 + g];
    }

    float h[8];
#pragma unroll
    for (int i = 0; i < 8; i++) h[i] = 0.f;
    short8 Bh, Bl;
#pragma unroll
    for (int j = 0; j < 8; j++) { Bh[j] = 0; Bl[j] = 0; }

    const int xrow = wv * 16 + s;

#pragma unroll 1
    for (int t = 0; t < TLEN; t++) {
        float xt = xs[xrow][t];
        floatx4 Dr0, Dr1, Dz0, Dz1, Dn0, Dn1;
#pragma unroll
        for (int r = 0; r < 4; r++) {
            Dr0[r] = fmaf(xt, u_r[r],     pr[r]);
            Dr1[r] = fmaf(xt, u_r[4 + r], pr[4 + r]);
            Dz0[r] = fmaf(xt, u_z[r],     pz[r]);
            Dz1[r] = fmaf(xt, u_z[4 + r], pz[4 + r]);
            Dn0[r] = 0.f; Dn1[r] = 0.f;
        }
        // 18 MFMAs: Whi*Bhi + Whi*Blo + Wlo*Bhi
        Dr0 = MFMA16(wh[0], Bh, Dr0); Dr0 = MFMA16(wh[0], Bl, Dr0); Dr0 = MFMA16(wl[0], Bh, Dr0);
        Dr1 = MFMA16(wh[1], Bh, Dr1); Dr1 = MFMA16(wh[1], Bl, Dr1); Dr1 = MFMA16(wl[1], Bh, Dr1);
        Dz0 = MFMA16(wh[2], Bh, Dz0); Dz0 = MFMA16(wh[2], Bl, Dz0); Dz0 = MFMA16(wl[2], Bh, Dz0);
        Dz1 = MFMA16(wh[3], Bh, Dz1); Dz1 = MFMA16(wh[3], Bl, Dz1); Dz1 = MFMA16(wl[3], Bh, Dz1);
        Dn0 = MFMA16(wh[4], Bh, Dn0); Dn0 = MFMA16(wh[4], Bl, Dn0); Dn0 = MFMA16(wl[4], Bh, Dn0);
        Dn1 = MFMA16(wh[5], Bh, Dn1); Dn1 = MFMA16(wh[5], Bl, Dn1); Dn1 = MFMA16(wl[5], Bh, Dn1);

        // gates + h update (all in-lane)
#pragma unroll
        for (int i = 0; i < 8; i++) {
            float dr = (i < 4) ? Dr0[i] : Dr1[i - 4];
            float dz = (i < 4) ? Dz0[i] : Dz1[i - 4];
            float dn = (i < 4) ? Dn0[i] : Dn1[i - 4];
            float rr = 1.f / (1.f + __expf(-dr));
            float zz = 1.f / (1.f + __expf(-dz));
            float pn = fmaf(rr, dn + bnh[i], fmaf(xt, u_n[i], bni[i]));
            float e = __expf(2.f * pn);
            float nn = 1.f - 2.f / (e + 1.f);
            h[i] = nn + zz * (h[i] - nn);
        }
        // split h -> bf16 hi/lo B-fragments (in-lane, k = 8u+i)
#pragma unroll
        for (int i = 0; i < 8; i++) {
            unsigned short hb = bf16_rne(h[i]);
            float lo = h[i] - bf16_tof(hb);
            Bh[i] = (short)hb;
            Bl[i] = (short)bf16_rne(lo);
        }
    }

    // ---- epilogue: xw1^T[o][s] = sum_g W1[g][o] * h[g][s] via 6 MFMAs ----
    short8 W1h[2], W1l[2];
#pragma unroll
    for (int tile = 0; tile < 2; tile++) {
        int o = tile * 16 + s;
        short8 a, b;
#pragma unroll
        for (int j = 0; j < 8; j++) {
            float wfull = W1[(8 * u + j) * 32 + o];
            unsigned short hb = bf16_rne(wfull);
            float lo = wfull - bf16_tof(hb);
            a[j] = (short)hb;
            b[j] = (short)bf16_rne(lo);
        }
        W1h[tile] = a; W1l[tile] = b;
    }
    floatx4 X0, X1;
#pragma unroll
    for (int r = 0; r < 4; r++) { X0[r] = 0.f; X1[r] = 0.f; }
    X0 = MFMA16(W1h[0], Bh, X0); X0 = MFMA16(W1h[0], Bl, X0); X0 = MFMA16(W1l[0], Bh, X0);
    X1 = MFMA16(W1h[1], Bh, X1); X1 = MFMA16(W1h[1], Bl, X1); X1 = MFMA16(W1l[1], Bh, X1);

    int seq = blockIdx.x * 64 + wv * 16 + s;
    if (seq >= BN) seq = BN - 1;
    float4 v0, v1;
    v0.x = X0[0]; v0.y = X0[1]; v0.z = X0[2]; v0.w = X0[3];
    v1.x = X1[0]; v1.y = X1[1]; v1.z = X1[2]; v1.w = X1[3];
    *reinterpret_cast<float4*>(xw1 + (size_t)seq * 32 + 4 * u) = v0;
    *reinterpret_cast<float4*>(xw1 + (size_t)seq * 32 + 16 + 4 * u) = v1;
}

// ---------------- graph prep: degree, dinv, CSR over tgt ----------------
__global__ void init_deg_cnt(float* deg, int* cnt, int N)
{
    int i = blockIdx.x * 256 + threadIdx.x;
    if (i < N) { deg[i] = 1.0f; cnt[i] = 1; }
}

__global__ void deg_accum(const int* __restrict__ src, const int* __restrict__ tgt,
                          const float* __restrict__ ew, float* deg, int* cnt, int E)
{
    int e = blockIdx.x * 256 + threadIdx.x;
    if (e < E) {
        int t = tgt[e];
        atomicAdd(&deg[t], ew[e]);
        atomicAdd(&cnt[t], 1);
    }
}

__global__ void dinv_kernel(const float* __restrict__ deg, float* dinv, int N)
{
    int i = blockIdx.x * 256 + threadIdx.x;
    if (i < N) {
        float d = deg[i];
        dinv[i] = d > 0.f ? rsqrtf(d) : 0.f;
    }
}

__global__ void scan_kernel(const int* __restrict__ cnt, int* offs, int* cursor, int N)
{
    __shared__ int sdata[1024];
    __shared__ int carry;
    int tid = threadIdx.x;
    if (tid == 0) { carry = 0; offs[0] = 0; }
    __syncthreads();
    for (int base = 0; base < N; base += 1024) {
        int i = base + tid;
        int v = (i < N) ? cnt[i] : 0;
        sdata[tid] = v;
        __syncthreads();
        int acc = v;
        for (int ofs = 1; ofs < 1024; ofs <<= 1) {
            int y = (tid >= ofs) ? sdata[tid - ofs] : 0;
            __syncthreads();
            acc += y;
            sdata[tid] = acc;
            __syncthreads();
        }
        if (i < N) {
            offs[i + 1] = carry + acc;
            cursor[i] = carry + acc - v;
        }
        __syncthreads();
        if (tid == 1023) carry += sdata[1023];
        __syncthreads();
    }
}

__global__ void fill_csr(const int* __restrict__ src, const int* __restrict__ tgt,
                         const float* __restrict__ ew, const float* __restrict__ dinv,
                         int* cursor, int* csr_src, float* csr_norm, int E, int N)
{
    int i = blockIdx.x * 256 + threadIdx.x;
    if (i < E) {
        int s = src[i], t = tgt[i];
        int pos = atomicAdd(&cursor[t], 1);
        csr_src[pos] = s;
        csr_norm[pos] = dinv[s] * ew[i] * dinv[t];
    } else if (i < E + N) {
        int n = i - E;
        int pos = atomicAdd(&cursor[n], 1);
        csr_src[pos] = n;
        csr_norm[pos] = dinv[n] * dinv[n];
    }
}

// ---------------- conv1: h1 = relu(gather-sum(xw1) + b1) ----------------
__global__ __launch_bounds__(256) void conv1_kernel(
    const float* __restrict__ xw1, const int* __restrict__ offs,
    const int* __restrict__ csrc, const float* __restrict__ cnorm,
    const float* __restrict__ b1, float* __restrict__ h1, int N)
{
    int wave = (blockIdx.x << 2) + (threadIdx.x >> 6);
    int lane = threadIdx.x & 63;
    int n = __builtin_amdgcn_readfirstlane(wave >> 3);
    int p = wave & 7;
    int f = lane & 31;
    int b = (p << 1) + (lane >> 5);
    int beg = __builtin_amdgcn_readfirstlane(offs[n]);
    int end = __builtin_amdgcn_readfirstlane(offs[n + 1]);
    int rowbase = b * N;
    float acc = 0.f;
    for (int i = beg; i < end; i++) {
        int s = csrc[i];
        float wn = cnorm[i];
        acc = fmaf(wn, xw1[((rowbase + s) << 5) + f], acc);
    }
    float v = acc + b1[f];
    h1[((rowbase + n) << 5) + f] = fmaxf(v, 0.f);
}

// ---------------- xw2 = h1 @ W2 (W2 stored [32,16]) ----------------
__global__ __launch_bounds__(256) void xw2_kernel(
    const float* __restrict__ h1, const float* __restrict__ W2,
    float* __restrict__ xw2, int BN)
{
    int m = blockIdx.x * 256 + threadIdx.x;
    if (m >= BN) return;
    float hin[32];
    const float4* hp = reinterpret_cast<const float4*>(h1 + (size_t)m * 32);
#pragma unroll
    for (int i = 0; i < 8; i++) {
        float4 v = hp[i];
        hin[4 * i] = v.x; hin[4 * i + 1] = v.y; hin[4 * i + 2] = v.z; hin[4 * i + 3] = v.w;
    }
    float4* op = reinterpret_cast<float4*>(xw2 + (size_t)m * 16);
#pragma unroll
    for (int oc = 0; oc < 4; oc++) {
        float tmp[4];
#pragma unroll
        for (int u = 0; u < 4; u++) {
            int o = oc * 4 + u;
            float a = 0.f;
#pragma unroll
            for (int j = 0; j < 32; j++) a = fmaf(hin[j], W2[j * 16 + o], a);
            tmp[u] = a;
        }
        float4 v; v.x = tmp[0]; v.y = tmp[1]; v.z = tmp[2]; v.w = tmp[3];
        op[oc] = v;
    }
}

// ---------------- conv2 + final linear ----------------
__global__ __launch_bounds__(256) void conv2_kernel(
    const float* __restrict__ xw2, const int* __restrict__ offs,
    const int* __restrict__ csrc, const float* __restrict__ cnorm,
    const float* __restrict__ b2, const float* __restrict__ Wfc,
    const float* __restrict__ bfc, float* __restrict__ out, int N)
{
    int wave = (blockIdx.x << 2) + (threadIdx.x >> 6);
    int lane = threadIdx.x & 63;
    int n = __builtin_amdgcn_readfirstlane(wave >> 2);
    int q = wave & 3;
    int f = lane & 15;
    int b = (q << 2) + (lane >> 4);
    int beg = __builtin_amdgcn_readfirstlane(offs[n]);
    int end = __builtin_amdgcn_readfirstlane(offs[n + 1]);
    float acc = 0.f;
    for (int i = beg; i < end; i++) {
        int s = csrc[i];
        float wn = cnorm[i];
        acc = fmaf(wn, xw2[((b * N + s) << 4) + f], acc);
    }
    float h2 = acc + b2[f];
    float prod = h2 * Wfc[f];
#pragma unroll
    for (int o = 1; o < 16; o <<= 1) prod += __shfl_xor(prod, o, 16);
    if (f == 0) out[b * N + n] = prod + bfc[0];
}

extern "C" void kernel_launch(void* const* d_in, const int* in_sizes, int n_in,
                              void* d_out, int out_size, void* d_ws, size_t ws_size,
                              hipStream_t stream)
{
    const float* x    = (const float*)d_in[0];
    const int*   eidx = (const int*)d_in[1];
    const float* ew   = (const float*)d_in[2];
    const float* w_ih = (const float*)d_in[3];
    const float* w_hh = (const float*)d_in[4];
    const float* b_ih = (const float*)d_in[5];
    const float* b_hh = (const float*)d_in[6];
    const float* W1   = (const float*)d_in[7];
    const float* b1   = (const float*)d_in[8];
    const float* W2   = (const float*)d_in[9];
    const float* b2   = (const float*)d_in[10];
    const float* Wfc  = (const float*)d_in[11];
    const float* bfc  = (const float*)d_in[12];

    const int E  = in_sizes[2];
    const int BN = in_sizes[0] / TLEN;   // 160000
    const int N  = NNODES;               // 10000
    const int* esrc = eidx;
    const int* etgt = eidx + E;
    float* out = (float*)d_out;

    char* w = (char*)d_ws;
    auto alloc = [&](size_t bytes) -> char* {
        char* p = w;
        w += (bytes + 255) / 256 * 256;
        return p;
    };
    float* xw1      = (float*)alloc((size_t)BN * 32 * 4);
    float* h1       = (float*)alloc((size_t)BN * 32 * 4);
    float* xw2      = (float*)alloc((size_t)BN * 16 * 4);
    float* deg      = (float*)alloc((size_t)N * 4);
    float* dinv     = (float*)alloc((size_t)N * 4);
    int*   cnt      = (int*)alloc((size_t)N * 4);
    int*   offs     = (int*)alloc((size_t)(N + 4) * 4);
    int*   cursor   = (int*)alloc((size_t)N * 4);
    int*   csr_src  = (int*)alloc((size_t)(E + N) * 4);
    float* csr_norm = (float*)alloc((size_t)(E + N) * 4);

    hipLaunchKernelGGL(init_deg_cnt, dim3((N + 255) / 256), dim3(256), 0, stream, deg, cnt, N);
    hipLaunchKernelGGL(deg_accum, dim3((E + 255) / 256), dim3(256), 0, stream, esrc, etgt, ew, deg, cnt, E);
    hipLaunchKernelGGL(dinv_kernel, dim3((N + 255) / 256), dim3(256), 0, stream, deg, dinv, N);
    hipLaunchKernelGGL(scan_kernel, dim3(1), dim3(1024), 0, stream, cnt, offs, cursor, N);
    hipLaunchKernelGGL(fill_csr, dim3((E + N + 255) / 256), dim3(256), 0, stream,
                       esrc, etgt, ew, dinv, cursor, csr_src, csr_norm, E, N);

    hipLaunchKernelGGL(gru_xw1_kernel, dim3((BN + 63) / 64), dim3(256), 0, stream,
                       x, w_ih, w_hh, b_ih, b_hh, W1, xw1, BN);
    hipLaunchKernelGGL(conv1_kernel, dim3(N * 2), dim3(256), 0, stream,
                       xw1, offs, csr_src, csr_norm, b1, h1, N);
    hipLaunchKernelGGL(xw2_kernel, dim3((BN + 255) / 256), dim3(256), 0, stream, h1, W2, xw2, BN);
    hipLaunchKernelGGL(conv2_kernel, dim3(N), dim3(256), 0, stream,
                       xw2, offs, csr_src, csr_norm, b2, Wfc, bfc, out, N);
}

// Round 5
// 320.320 us; speedup vs baseline: 4.0533x; 1.2800x over previous
//
#include <hip/hip_runtime.h>

#define TLEN 24
#define HID 32
#define NNODES 10000

typedef __attribute__((ext_vector_type(8))) short short8;
typedef __attribute__((ext_vector_type(4))) float floatx4;
typedef __attribute__((ext_vector_type(4))) int int4v;

__device__ __forceinline__ unsigned short bf16_rne(float f) {
    unsigned u = __float_as_uint(f);
    unsigned r = u + 0x7fffu + ((u >> 16) & 1u);
    return (unsigned short)(r >> 16);
}
__device__ __forceinline__ float bf16_tof(unsigned short b) {
    return __uint_as_float(((unsigned)b) << 16);
}
__device__ __forceinline__ unsigned cvt_pk_bf16(float a, float b) {
    unsigned r;
    asm("v_cvt_pk_bf16_f32 %0, %1, %2" : "=v"(r) : "v"(a), "v"(b));
    return r;  // low16 = bf16(a), high16 = bf16(b)
}
// split pair (a,b) into bf16 hi dword + bf16 lo-residual dword
__device__ __forceinline__ void split_pair(float a, float b, unsigned& hi, unsigned& lo) {
    hi = cvt_pk_bf16(a, b);
    float ar = __uint_as_float(hi << 16);
    float br = __uint_as_float(hi & 0xffff0000u);
    lo = cvt_pk_bf16(a - ar, b - br);
}

#define MFMA16(a, b, c) __builtin_amdgcn_mfma_f32_16x16x32_bf16((a), (b), (c), 0, 0, 0)

// ---------------- GRU via MFMA, 16 seqs per wave ----------------
// Lane l: u=l>>4, s=l&15. D-reg i of tile-pair = gate g=8u+i, seq s; h stays
// in-lane as next step's B k-slice. Weights/consts prescaled into exp2 domain
// (r,z by log2e; n by 2log2e) and PINNED in VGPRs via asm.
__global__ __launch_bounds__(256, 1) void gru_xw1_kernel(
    const float* __restrict__ x, const float* __restrict__ w_ih,
    const float* __restrict__ w_hh, const float* __restrict__ b_ih,
    const float* __restrict__ b_hh, const float* __restrict__ W1,
    float* __restrict__ xw1, int BN)
{
    __shared__ float xs[64][25];
    const int tid = threadIdx.x;
    const int wv = tid >> 6, lane = tid & 63;
    const int u = lane >> 4;
    const int s = lane & 15;

    for (int i = tid; i < 64 * TLEN; i += 256) {
        int sl = i / TLEN, t = i - sl * TLEN;
        int gseq = blockIdx.x * 64 + sl;
        if (gseq >= BN) gseq = BN - 1;
        xs[sl][t] = x[(size_t)gseq * TLEN + t];
    }
    __syncthreads();

    const float sc_rz = 1.4426950408889634f;       // log2(e)
    const float sc_n  = 2.8853900817779268f;       // 2*log2(e)

    // ---- w_hh A-fragments (hi/lo), permuted rows, prescaled ----
    const int arow_g = 8 * (s >> 2) + (s & 3);
    short8 wh[6], wl[6];
#pragma unroll
    for (int G = 0; G < 3; G++) {
        float sc = (G == 2) ? sc_n : sc_rz;
#pragma unroll
        for (int hf = 0; hf < 2; hf++) {
            int row = G * 32 + arow_g + 4 * hf;
            const float* wp = w_hh + row * 32 + 8 * u;
            unsigned hib[4], lob[4];
#pragma unroll
            for (int p = 0; p < 4; p++)
                split_pair(wp[2 * p] * sc, wp[2 * p + 1] * sc, hib[p], lob[p]);
            int4v hv = {(int)hib[0], (int)hib[1], (int)hib[2], (int)hib[3]};
            int4v lv = {(int)lob[0], (int)lob[1], (int)lob[2], (int)lob[3]};
            wh[G * 2 + hf] = __builtin_bit_cast(short8, hv);
            wl[G * 2 + hf] = __builtin_bit_cast(short8, lv);
        }
    }

    // ---- per-lane gate constants (g = 8u + hf*4 + r), prescaled ----
    floatx4 CUR[2], CPR[2], CUZ[2], CPZ[2], CUN[2], CBNI[2], CBNH[2];
#pragma unroll
    for (int hf = 0; hf < 2; hf++) {
#pragma unroll
        for (int r = 0; r < 4; r++) {
            int g = 8 * u + hf * 4 + r;
            CUR[hf][r]  = w_ih[g] * sc_rz;
            CPR[hf][r]  = (b_ih[g] + b_hh[g]) * sc_rz;
            CUZ[hf][r]  = w_ih[32 + g] * sc_rz;
            CPZ[hf][r]  = (b_ih[32 + g] + b_hh[32 + g]) * sc_rz;
            CUN[hf][r]  = w_ih[64 + g] * sc_n;
            CBNI[hf][r] = b_ih[64 + g] * sc_n;
            CBNH[hf][r] = b_hh[64 + g] * sc_n;
        }
    }

    // ---- pin everything loop-invariant in VGPRs ----
    asm volatile("" : "+v"(wh[0]), "+v"(wh[1]), "+v"(wh[2]), "+v"(wh[3]),
                      "+v"(wh[4]), "+v"(wh[5]), "+v"(wl[0]), "+v"(wl[1]),
                      "+v"(wl[2]), "+v"(wl[3]), "+v"(wl[4]), "+v"(wl[5]));
    asm volatile("" : "+v"(CUR[0]), "+v"(CUR[1]), "+v"(CPR[0]), "+v"(CPR[1]),
                      "+v"(CUZ[0]), "+v"(CUZ[1]), "+v"(CPZ[0]), "+v"(CPZ[1]));
    asm volatile("" : "+v"(CUN[0]), "+v"(CUN[1]), "+v"(CBNI[0]), "+v"(CBNI[1]),
                      "+v"(CBNH[0]), "+v"(CBNH[1]));

    float h[8];
#pragma unroll
    for (int i = 0; i < 8; i++) h[i] = 0.f;
    short8 Bh = {0, 0, 0, 0, 0, 0, 0, 0}, Bl = {0, 0, 0, 0, 0, 0, 0, 0};

    const int xrow = wv * 16 + s;

#pragma unroll 1
    for (int t = 0; t < TLEN; t++) {
        float xt = xs[xrow][t];
        floatx4 Dr0, Dr1, Dz0, Dz1;
        floatx4 Dn0 = CBNH[0], Dn1 = CBNH[1];
#pragma unroll
        for (int r = 0; r < 4; r++) {
            Dr0[r] = fmaf(xt, CUR[0][r], CPR[0][r]);
            Dr1[r] = fmaf(xt, CUR[1][r], CPR[1][r]);
            Dz0[r] = fmaf(xt, CUZ[0][r], CPZ[0][r]);
            Dz1[r] = fmaf(xt, CUZ[1][r], CPZ[1][r]);
        }
        Dr0 = MFMA16(wh[0], Bh, Dr0); Dr0 = MFMA16(wh[0], Bl, Dr0); Dr0 = MFMA16(wl[0], Bh, Dr0);
        Dr1 = MFMA16(wh[1], Bh, Dr1); Dr1 = MFMA16(wh[1], Bl, Dr1); Dr1 = MFMA16(wl[1], Bh, Dr1);
        Dz0 = MFMA16(wh[2], Bh, Dz0); Dz0 = MFMA16(wh[2], Bl, Dz0); Dz0 = MFMA16(wl[2], Bh, Dz0);
        Dz1 = MFMA16(wh[3], Bh, Dz1); Dz1 = MFMA16(wh[3], Bl, Dz1); Dz1 = MFMA16(wl[3], Bh, Dz1);
        Dn0 = MFMA16(wh[4], Bh, Dn0); Dn0 = MFMA16(wh[4], Bl, Dn0); Dn0 = MFMA16(wl[4], Bh, Dn0);
        Dn1 = MFMA16(wh[5], Bh, Dn1); Dn1 = MFMA16(wh[5], Bl, Dn1); Dn1 = MFMA16(wl[5], Bh, Dn1);

        // gates in exp2 domain (all in-lane)
#pragma unroll
        for (int i = 0; i < 8; i++) {
            float dr = (i < 4) ? Dr0[i] : Dr1[i - 4];
            float dz = (i < 4) ? Dz0[i] : Dz1[i - 4];
            float dn = (i < 4) ? Dn0[i] : Dn1[i - 4];
            float rr = __builtin_amdgcn_rcpf(1.f + __builtin_amdgcn_exp2f(-dr));
            float zz = __builtin_amdgcn_rcpf(1.f + __builtin_amdgcn_exp2f(-dz));
            float gxn = fmaf(xt, CUN[i >> 2][i & 3], CBNI[i >> 2][i & 3]);
            float pn2 = fmaf(rr, dn, gxn);
            float e2 = __builtin_amdgcn_exp2f(pn2);
            float tnh = fmaf(-2.f, __builtin_amdgcn_rcpf(e2 + 1.f), 1.f);
            h[i] = fmaf(zz, h[i] - tnh, tnh);
        }
        // pack h -> bf16 hi/lo fragments via v_cvt_pk_bf16_f32
        unsigned hb[4], lb[4];
#pragma unroll
        for (int p = 0; p < 4; p++) split_pair(h[2 * p], h[2 * p + 1], hb[p], lb[p]);
        int4v hv = {(int)hb[0], (int)hb[1], (int)hb[2], (int)hb[3]};
        int4v lv = {(int)lb[0], (int)lb[1], (int)lb[2], (int)lb[3]};
        Bh = __builtin_bit_cast(short8, hv);
        Bl = __builtin_bit_cast(short8, lv);
    }

    // ---- epilogue: xw1^T[o][s] = sum_g W1[g][o] * h[g][s] via 6 MFMAs ----
    short8 W1h[2], W1l[2];
#pragma unroll
    for (int tile = 0; tile < 2; tile++) {
        int o = tile * 16 + s;
        short8 a, b;
#pragma unroll
        for (int j = 0; j < 8; j++) {
            float wfull = W1[(8 * u + j) * 32 + o];
            unsigned short hbb = bf16_rne(wfull);
            float lo = wfull - bf16_tof(hbb);
            a[j] = (short)hbb;
            b[j] = (short)bf16_rne(lo);
        }
        W1h[tile] = a; W1l[tile] = b;
    }
    floatx4 X0, X1;
#pragma unroll
    for (int r = 0; r < 4; r++) { X0[r] = 0.f; X1[r] = 0.f; }
    X0 = MFMA16(W1h[0], Bh, X0); X0 = MFMA16(W1h[0], Bl, X0); X0 = MFMA16(W1l[0], Bh, X0);
    X1 = MFMA16(W1h[1], Bh, X1); X1 = MFMA16(W1h[1], Bl, X1); X1 = MFMA16(W1l[1], Bh, X1);

    int seq = blockIdx.x * 64 + wv * 16 + s;
    if (seq >= BN) seq = BN - 1;
    float4 v0, v1;
    v0.x = X0[0]; v0.y = X0[1]; v0.z = X0[2]; v0.w = X0[3];
    v1.x = X1[0]; v1.y = X1[1]; v1.z = X1[2]; v1.w = X1[3];
    *reinterpret_cast<float4*>(xw1 + (size_t)seq * 32 + 4 * u) = v0;
    *reinterpret_cast<float4*>(xw1 + (size_t)seq * 32 + 16 + 4 * u) = v1;
}

// ---------------- graph prep: degree, dinv, CSR over tgt ----------------
__global__ void init_deg_cnt(float* deg, int* cnt, int N)
{
    int i = blockIdx.x * 256 + threadIdx.x;
    if (i < N) { deg[i] = 1.0f; cnt[i] = 1; }
}

__global__ void deg_accum(const int* __restrict__ src, const int* __restrict__ tgt,
                          const float* __restrict__ ew, float* deg, int* cnt, int E)
{
    int e = blockIdx.x * 256 + threadIdx.x;
    if (e < E) {
        int t = tgt[e];
        atomicAdd(&deg[t], ew[e]);
        atomicAdd(&cnt[t], 1);
    }
}

__global__ void dinv_kernel(const float* __restrict__ deg, float* dinv, int N)
{
    int i = blockIdx.x * 256 + threadIdx.x;
    if (i < N) {
        float d = deg[i];
        dinv[i] = d > 0.f ? rsqrtf(d) : 0.f;
    }
}

__global__ void scan_kernel(const int* __restrict__ cnt, int* offs, int* cursor, int N)
{
    __shared__ int sdata[1024];
    __shared__ int carry;
    int tid = threadIdx.x;
    if (tid == 0) { carry = 0; offs[0] = 0; }
    __syncthreads();
    for (int base = 0; base < N; base += 1024) {
        int i = base + tid;
        int v = (i < N) ? cnt[i] : 0;
        sdata[tid] = v;
        __syncthreads();
        int acc = v;
        for (int ofs = 1; ofs < 1024; ofs <<= 1) {
            int y = (tid >= ofs) ? sdata[tid - ofs] : 0;
            __syncthreads();
            acc += y;
            sdata[tid] = acc;
            __syncthreads();
        }
        if (i < N) {
            offs[i + 1] = carry + acc;
            cursor[i] = carry + acc - v;
        }
        __syncthreads();
        if (tid == 1023) carry += sdata[1023];
        __syncthreads();
    }
}

__global__ void fill_csr(const int* __restrict__ src, const int* __restrict__ tgt,
                         const float* __restrict__ ew, const float* __restrict__ dinv,
                         int* cursor, int* csr_src, float* csr_norm, int E, int N)
{
    int i = blockIdx.x * 256 + threadIdx.x;
    if (i < E) {
        int s = src[i], t = tgt[i];
        int pos = atomicAdd(&cursor[t], 1);
        csr_src[pos] = s;
        csr_norm[pos] = dinv[s] * ew[i] * dinv[t];
    } else if (i < E + N) {
        int n = i - E;
        int pos = atomicAdd(&cursor[n], 1);
        csr_src[pos] = n;
        csr_norm[pos] = dinv[n] * dinv[n];
    }
}

// ---------------- conv1: h1 = relu(gather-sum(xw1) + b1) ----------------
__global__ __launch_bounds__(256) void conv1_kernel(
    const float* __restrict__ xw1, const int* __restrict__ offs,
    const int* __restrict__ csrc, const float* __restrict__ cnorm,
    const float* __restrict__ b1, float* __restrict__ h1, int N)
{
    int wave = (blockIdx.x << 2) + (threadIdx.x >> 6);
    int lane = threadIdx.x & 63;
    int n = __builtin_amdgcn_readfirstlane(wave >> 3);
    int p = wave & 7;
    int f = lane & 31;
    int b = (p << 1) + (lane >> 5);
    int beg = __builtin_amdgcn_readfirstlane(offs[n]);
    int end = __builtin_amdgcn_readfirstlane(offs[n + 1]);
    int rowbase = b * N;
    float acc = 0.f;
    for (int i = beg; i < end; i++) {
        int s = csrc[i];
        float wn = cnorm[i];
        acc = fmaf(wn, xw1[((rowbase + s) << 5) + f], acc);
    }
    float v = acc + b1[f];
    h1[((rowbase + n) << 5) + f] = fmaxf(v, 0.f);
}

// ---------------- xw2 = h1 @ W2 (W2 stored [32,16]) ----------------
__global__ __launch_bounds__(256) void xw2_kernel(
    const float* __restrict__ h1, const float* __restrict__ W2,
    float* __restrict__ xw2, int BN)
{
    int m = blockIdx.x * 256 + threadIdx.x;
    if (m >= BN) return;
    float hin[32];
    const float4* hp = reinterpret_cast<const float4*>(h1 + (size_t)m * 32);
#pragma unroll
    for (int i = 0; i < 8; i++) {
        float4 v = hp[i];
        hin[4 * i] = v.x; hin[4 * i + 1] = v.y; hin[4 * i + 2] = v.z; hin[4 * i + 3] = v.w;
    }
    float4* op = reinterpret_cast<float4*>(xw2 + (size_t)m * 16);
#pragma unroll
    for (int oc = 0; oc < 4; oc++) {
        float tmp[4];
#pragma unroll
        for (int u = 0; u < 4; u++) {
            int o = oc * 4 + u;
            float a = 0.f;
#pragma unroll
            for (int j = 0; j < 32; j++) a = fmaf(hin[j], W2[j * 16 + o], a);
            tmp[u] = a;
        }
        float4 v; v.x = tmp[0]; v.y = tmp[1]; v.z = tmp[2]; v.w = tmp[3];
        op[oc] = v;
    }
}

// ---------------- conv2 + final linear ----------------
__global__ __launch_bounds__(256) void conv2_kernel(
    const float* __restrict__ xw2, const int* __restrict__ offs,
    const int* __restrict__ csrc, const float* __restrict__ cnorm,
    const float* __restrict__ b2, const float* __restrict__ Wfc,
    const float* __restrict__ bfc, float* __restrict__ out, int N)
{
    int wave = (blockIdx.x << 2) + (threadIdx.x >> 6);
    int lane = threadIdx.x & 63;
    int n = __builtin_amdgcn_readfirstlane(wave >> 2);
    int q = wave & 3;
    int f = lane & 15;
    int b = (q << 2) + (lane >> 4);
    int beg = __builtin_amdgcn_readfirstlane(offs[n]);
    int end = __builtin_amdgcn_readfirstlane(offs[n + 1]);
    float acc = 0.f;
    for (int i = beg; i < end; i++) {
        int s = csrc[i];
        float wn = cnorm[i];
        acc = fmaf(wn, xw2[((b * N + s) << 4) + f], acc);
    }
    float h2 = acc + b2[f];
    float prod = h2 * Wfc[f];
#pragma unroll
    for (int o = 1; o < 16; o <<= 1) prod += __shfl_xor(prod, o, 16);
    if (f == 0) out[b * N + n] = prod + bfc[0];
}

extern "C" void kernel_launch(void* const* d_in, const int* in_sizes, int n_in,
                              void* d_out, int out_size, void* d_ws, size_t ws_size,
                              hipStream_t stream)
{
    const float* x    = (const float*)d_in[0];
    const int*   eidx = (const int*)d_in[1];
    const float* ew   = (const float*)d_in[2];
    const float* w_ih = (const float*)d_in[3];
    const float* w_hh = (const float*)d_in[4];
    const float* b_ih = (const float*)d_in[5];
    const float* b_hh = (const float*)d_in[6];
    const float* W1   = (const float*)d_in[7];
    const float* b1   = (const float*)d_in[8];
    const float* W2   = (const float*)d_in[9];
    const float* b2   = (const float*)d_in[10];
    const float* Wfc  = (const float*)d_in[11];
    const float* bfc  = (const float*)d_in[12];

    const int E  = in_sizes[2];
    const int BN = in_sizes[0] / TLEN;   // 160000
    const int N  = NNODES;               // 10000
    const int* esrc = eidx;
    const int* etgt = eidx + E;
    float* out = (float*)d_out;

    char* w = (char*)d_ws;
    auto alloc = [&](size_t bytes) -> char* {
        char* p = w;
        w += (bytes + 255) / 256 * 256;
        return p;
    };
    float* xw1      = (float*)alloc((size_t)BN * 32 * 4);
    float* h1       = (float*)alloc((size_t)BN * 32 * 4);
    float* xw2      = (float*)alloc((size_t)BN * 16 * 4);
    float* deg      = (float*)alloc((size_t)N * 4);
    float* dinv     = (float*)alloc((size_t)N * 4);
    int*   cnt      = (int*)alloc((size_t)N * 4);
    int*   offs     = (int*)alloc((size_t)(N + 4) * 4);
    int*   cursor   = (int*)alloc((size_t)N * 4);
    int*   csr_src  = (int*)alloc((size_t)(E + N) * 4);
    float* csr_norm = (float*)alloc((size_t)(E + N) * 4);

    hipLaunchKernelGGL(init_deg_cnt, dim3((N + 255) / 256), dim3(256), 0, stream, deg, cnt, N);
    hipLaunchKernelGGL(deg_accum, dim3((E + 255) / 256), dim3(256), 0, stream, esrc, etgt, ew, deg, cnt, E);
    hipLaunchKernelGGL(dinv_kernel, dim3((N + 255) / 256), dim3(256), 0, stream, deg, dinv, N);
    hipLaunchKernelGGL(scan_kernel, dim3(1), dim3(1024), 0, stream, cnt, offs, cursor, N);
    hipLaunchKernelGGL(fill_csr, dim3((E + N + 255) / 256), dim3(256), 0, stream,
                       esrc, etgt, ew, dinv, cursor, csr_src, csr_norm, E, N);

    hipLaunchKernelGGL(gru_xw1_kernel, dim3((BN + 63) / 64), dim3(256), 0, stream,
                       x, w_ih, w_hh, b_ih, b_hh, W1, xw1, BN);
    hipLaunchKernelGGL(conv1_kernel, dim3(N * 2), dim3(256), 0, stream,
                       xw1, offs, csr_src, csr_norm, b1, h1, N);
    hipLaunchKernelGGL(xw2_kernel, dim3((BN + 255) / 256), dim3(256), 0, stream, h1, W2, xw2, BN);
    hipLaunchKernelGGL(conv2_kernel, dim3(N), dim3(256), 0, stream,
                       xw2, offs, csr_src, csr_norm, b2, Wfc, bfc, out, N);
}

// Round 6
// 303.893 us; speedup vs baseline: 4.2724x; 1.0541x over previous
//
#include <hip/hip_runtime.h>

#define TLEN 24
#define HID 32
#define NNODES 10000

typedef __attribute__((ext_vector_type(8))) short short8;
typedef __attribute__((ext_vector_type(4))) float floatx4;
typedef __attribute__((ext_vector_type(4))) int int4v;

__device__ __forceinline__ unsigned short bf16_rne(float f) {
    unsigned u = __float_as_uint(f);
    unsigned r = u + 0x7fffu + ((u >> 16) & 1u);
    return (unsigned short)(r >> 16);
}
__device__ __forceinline__ float bf16_tof(unsigned short b) {
    return __uint_as_float(((unsigned)b) << 16);
}
__device__ __forceinline__ unsigned cvt_pk_bf16(float a, float b) {
    unsigned r;
    asm("v_cvt_pk_bf16_f32 %0, %1, %2" : "=v"(r) : "v"(a), "v"(b));
    return r;  // low16 = bf16(a), high16 = bf16(b)
}
// split pair (a,b) into bf16 hi dword + bf16 lo-residual dword
__device__ __forceinline__ void split_pair(float a, float b, unsigned& hi, unsigned& lo) {
    hi = cvt_pk_bf16(a, b);
    float ar = __uint_as_float(hi << 16);
    float br = __uint_as_float(hi & 0xffff0000u);
    lo = cvt_pk_bf16(a - ar, b - br);
}

#define MFMA16(a, b, c) __builtin_amdgcn_mfma_f32_16x16x32_bf16((a), (b), (c), 0, 0, 0)

// ---------------- GRU via MFMA, 16 seqs per wave ----------------
// Lane l: u=l>>4, s=l&15. D-reg i of tile-pair = gate g=8u+i, seq s; h stays
// in-lane as next step's B k-slice. Weights/consts prescaled into exp2 domain
// (r,z by log2e; n by 2log2e). launch_bounds(256,3): min 3 waves/EU -> VGPR
// cap ~170 >= ~156 live values -> all-arch-VGPR allocation, no AGPR copies.
__global__ __launch_bounds__(256, 3) void gru_xw1_kernel(
    const float* __restrict__ x, const float* __restrict__ w_ih,
    const float* __restrict__ w_hh, const float* __restrict__ b_ih,
    const float* __restrict__ b_hh, const float* __restrict__ W1,
    float* __restrict__ xw1, int BN)
{
    __shared__ float xs[64][25];
    const int tid = threadIdx.x;
    const int wv = tid >> 6, lane = tid & 63;
    const int u = lane >> 4;
    const int s = lane & 15;

    for (int i = tid; i < 64 * TLEN; i += 256) {
        int sl = i / TLEN, t = i - sl * TLEN;
        int gseq = blockIdx.x * 64 + sl;
        if (gseq >= BN) gseq = BN - 1;
        xs[sl][t] = x[(size_t)gseq * TLEN + t];
    }
    __syncthreads();

    const float sc_rz = 1.4426950408889634f;       // log2(e)
    const float sc_n  = 2.8853900817779268f;       // 2*log2(e)

    // ---- w_hh A-fragments (hi/lo), permuted rows, prescaled ----
    const int arow_g = 8 * (s >> 2) + (s & 3);
    short8 wh[6], wl[6];
#pragma unroll
    for (int G = 0; G < 3; G++) {
        float sc = (G == 2) ? sc_n : sc_rz;
#pragma unroll
        for (int hf = 0; hf < 2; hf++) {
            int row = G * 32 + arow_g + 4 * hf;
            const float* wp = w_hh + row * 32 + 8 * u;
            unsigned hib[4], lob[4];
#pragma unroll
            for (int p = 0; p < 4; p++)
                split_pair(wp[2 * p] * sc, wp[2 * p + 1] * sc, hib[p], lob[p]);
            int4v hv = {(int)hib[0], (int)hib[1], (int)hib[2], (int)hib[3]};
            int4v lv = {(int)lob[0], (int)lob[1], (int)lob[2], (int)lob[3]};
            wh[G * 2 + hf] = __builtin_bit_cast(short8, hv);
            wl[G * 2 + hf] = __builtin_bit_cast(short8, lv);
        }
    }

    // ---- per-lane gate constants (g = 8u + hf*4 + r), prescaled ----
    floatx4 CUR[2], CPR[2], CUZ[2], CPZ[2], CUN[2], CBNI[2], CBNH[2];
#pragma unroll
    for (int hf = 0; hf < 2; hf++) {
#pragma unroll
        for (int r = 0; r < 4; r++) {
            int g = 8 * u + hf * 4 + r;
            CUR[hf][r]  = w_ih[g] * sc_rz;
            CPR[hf][r]  = (b_ih[g] + b_hh[g]) * sc_rz;
            CUZ[hf][r]  = w_ih[32 + g] * sc_rz;
            CPZ[hf][r]  = (b_ih[32 + g] + b_hh[32 + g]) * sc_rz;
            CUN[hf][r]  = w_ih[64 + g] * sc_n;
            CBNI[hf][r] = b_ih[64 + g] * sc_n;
            CBNH[hf][r] = b_hh[64 + g] * sc_n;
        }
    }

    // ---- pin loop-invariants in VGPRs (blocks rematerialization) ----
    asm volatile("" : "+v"(wh[0]), "+v"(wh[1]), "+v"(wh[2]), "+v"(wh[3]),
                      "+v"(wh[4]), "+v"(wh[5]), "+v"(wl[0]), "+v"(wl[1]),
                      "+v"(wl[2]), "+v"(wl[3]), "+v"(wl[4]), "+v"(wl[5]));
    asm volatile("" : "+v"(CUR[0]), "+v"(CUR[1]), "+v"(CPR[0]), "+v"(CPR[1]),
                      "+v"(CUZ[0]), "+v"(CUZ[1]), "+v"(CPZ[0]), "+v"(CPZ[1]));
    asm volatile("" : "+v"(CUN[0]), "+v"(CUN[1]), "+v"(CBNI[0]), "+v"(CBNI[1]),
                      "+v"(CBNH[0]), "+v"(CBNH[1]));

    float h[8];
#pragma unroll
    for (int i = 0; i < 8; i++) h[i] = 0.f;
    short8 Bh = {0, 0, 0, 0, 0, 0, 0, 0}, Bl = {0, 0, 0, 0, 0, 0, 0, 0};

    const int xrow = wv * 16 + s;

#pragma unroll 1
    for (int t = 0; t < TLEN; t++) {
        float xt = xs[xrow][t];
        floatx4 Dr0, Dr1, Dz0, Dz1;
        floatx4 Dn0 = CBNH[0], Dn1 = CBNH[1];
#pragma unroll
        for (int r = 0; r < 4; r++) {
            Dr0[r] = fmaf(xt, CUR[0][r], CPR[0][r]);
            Dr1[r] = fmaf(xt, CUR[1][r], CPR[1][r]);
            Dz0[r] = fmaf(xt, CUZ[0][r], CPZ[0][r]);
            Dz1[r] = fmaf(xt, CUZ[1][r], CPZ[1][r]);
        }
        Dr0 = MFMA16(wh[0], Bh, Dr0); Dr0 = MFMA16(wh[0], Bl, Dr0); Dr0 = MFMA16(wl[0], Bh, Dr0);
        Dr1 = MFMA16(wh[1], Bh, Dr1); Dr1 = MFMA16(wh[1], Bl, Dr1); Dr1 = MFMA16(wl[1], Bh, Dr1);
        Dz0 = MFMA16(wh[2], Bh, Dz0); Dz0 = MFMA16(wh[2], Bl, Dz0); Dz0 = MFMA16(wl[2], Bh, Dz0);
        Dz1 = MFMA16(wh[3], Bh, Dz1); Dz1 = MFMA16(wh[3], Bl, Dz1); Dz1 = MFMA16(wl[3], Bh, Dz1);
        Dn0 = MFMA16(wh[4], Bh, Dn0); Dn0 = MFMA16(wh[4], Bl, Dn0); Dn0 = MFMA16(wl[4], Bh, Dn0);
        Dn1 = MFMA16(wh[5], Bh, Dn1); Dn1 = MFMA16(wh[5], Bl, Dn1); Dn1 = MFMA16(wl[5], Bh, Dn1);

        // gates in exp2 domain (all in-lane)
#pragma unroll
        for (int i = 0; i < 8; i++) {
            float dr = (i < 4) ? Dr0[i] : Dr1[i - 4];
            float dz = (i < 4) ? Dz0[i] : Dz1[i - 4];
            float dn = (i < 4) ? Dn0[i] : Dn1[i - 4];
            float rr = __builtin_amdgcn_rcpf(1.f + __builtin_amdgcn_exp2f(-dr));
            float zz = __builtin_amdgcn_rcpf(1.f + __builtin_amdgcn_exp2f(-dz));
            float gxn = fmaf(xt, CUN[i >> 2][i & 3], CBNI[i >> 2][i & 3]);
            float pn2 = fmaf(rr, dn, gxn);
            float e2 = __builtin_amdgcn_exp2f(pn2);
            float tnh = fmaf(-2.f, __builtin_amdgcn_rcpf(e2 + 1.f), 1.f);
            h[i] = fmaf(zz, h[i] - tnh, tnh);
        }
        // pack h -> bf16 hi/lo fragments via v_cvt_pk_bf16_f32
        unsigned hb[4], lb[4];
#pragma unroll
        for (int p = 0; p < 4; p++) split_pair(h[2 * p], h[2 * p + 1], hb[p], lb[p]);
        int4v hv = {(int)hb[0], (int)hb[1], (int)hb[2], (int)hb[3]};
        int4v lv = {(int)lb[0], (int)lb[1], (int)lb[2], (int)lb[3]};
        Bh = __builtin_bit_cast(short8, hv);
        Bl = __builtin_bit_cast(short8, lv);
    }

    // ---- epilogue: xw1^T[o][s] = sum_g W1[g][o] * h[g][s] via 6 MFMAs ----
    short8 W1h[2], W1l[2];
#pragma unroll
    for (int tile = 0; tile < 2; tile++) {
        int o = tile * 16 + s;
        short8 a, b;
#pragma unroll
        for (int j = 0; j < 8; j++) {
            float wfull = W1[(8 * u + j) * 32 + o];
            unsigned short hbb = bf16_rne(wfull);
            float lo = wfull - bf16_tof(hbb);
            a[j] = (short)hbb;
            b[j] = (short)bf16_rne(lo);
        }
        W1h[tile] = a; W1l[tile] = b;
    }
    floatx4 X0, X1;
#pragma unroll
    for (int r = 0; r < 4; r++) { X0[r] = 0.f; X1[r] = 0.f; }
    X0 = MFMA16(W1h[0], Bh, X0); X0 = MFMA16(W1h[0], Bl, X0); X0 = MFMA16(W1l[0], Bh, X0);
    X1 = MFMA16(W1h[1], Bh, X1); X1 = MFMA16(W1h[1], Bl, X1); X1 = MFMA16(W1l[1], Bh, X1);

    int seq = blockIdx.x * 64 + wv * 16 + s;
    if (seq >= BN) seq = BN - 1;
    float4 v0, v1;
    v0.x = X0[0]; v0.y = X0[1]; v0.z = X0[2]; v0.w = X0[3];
    v1.x = X1[0]; v1.y = X1[1]; v1.z = X1[2]; v1.w = X1[3];
    *reinterpret_cast<float4*>(xw1 + (size_t)seq * 32 + 4 * u) = v0;
    *reinterpret_cast<float4*>(xw1 + (size_t)seq * 32 + 16 + 4 * u) = v1;
}

// ---------------- graph prep: degree, dinv, CSR over tgt ----------------
__global__ void init_deg_cnt(float* deg, int* cnt, int N)
{
    int i = blockIdx.x * 256 + threadIdx.x;
    if (i < N) { deg[i] = 1.0f; cnt[i] = 1; }
}

__global__ void deg_accum(const int* __restrict__ src, const int* __restrict__ tgt,
                          const float* __restrict__ ew, float* deg, int* cnt, int E)
{
    int e = blockIdx.x * 256 + threadIdx.x;
    if (e < E) {
        int t = tgt[e];
        atomicAdd(&deg[t], ew[e]);
        atomicAdd(&cnt[t], 1);
    }
}

__global__ void dinv_kernel(const float* __restrict__ deg, float* dinv, int N)
{
    int i = blockIdx.x * 256 + threadIdx.x;
    if (i < N) {
        float d = deg[i];
        dinv[i] = d > 0.f ? rsqrtf(d) : 0.f;
    }
}

__global__ void scan_kernel(const int* __restrict__ cnt, int* offs, int* cursor, int N)
{
    __shared__ int sdata[1024];
    __shared__ int carry;
    int tid = threadIdx.x;
    if (tid == 0) { carry = 0; offs[0] = 0; }
    __syncthreads();
    for (int base = 0; base < N; base += 1024) {
        int i = base + tid;
        int v = (i < N) ? cnt[i] : 0;
        sdata[tid] = v;
        __syncthreads();
        int acc = v;
        for (int ofs = 1; ofs < 1024; ofs <<= 1) {
            int y = (tid >= ofs) ? sdata[tid - ofs] : 0;
            __syncthreads();
            acc += y;
            sdata[tid] = acc;
            __syncthreads();
        }
        if (i < N) {
            offs[i + 1] = carry + acc;
            cursor[i] = carry + acc - v;
        }
        __syncthreads();
        if (tid == 1023) carry += sdata[1023];
        __syncthreads();
    }
}

__global__ void fill_csr(const int* __restrict__ src, const int* __restrict__ tgt,
                         const float* __restrict__ ew, const float* __restrict__ dinv,
                         int* cursor, int* csr_src, float* csr_norm, int E, int N)
{
    int i = blockIdx.x * 256 + threadIdx.x;
    if (i < E) {
        int s = src[i], t = tgt[i];
        int pos = atomicAdd(&cursor[t], 1);
        csr_src[pos] = s;
        csr_norm[pos] = dinv[s] * ew[i] * dinv[t];
    } else if (i < E + N) {
        int n = i - E;
        int pos = atomicAdd(&cursor[n], 1);
        csr_src[pos] = n;
        csr_norm[pos] = dinv[n] * dinv[n];
    }
}

// ---------------- conv1: h1 = relu(gather-sum(xw1) + b1) ----------------
__global__ __launch_bounds__(256) void conv1_kernel(
    const float* __restrict__ xw1, const int* __restrict__ offs,
    const int* __restrict__ csrc, const float* __restrict__ cnorm,
    const float* __restrict__ b1, float* __restrict__ h1, int N)
{
    int wave = (blockIdx.x << 2) + (threadIdx.x >> 6);
    int lane = threadIdx.x & 63;
    int n = __builtin_amdgcn_readfirstlane(wave >> 3);
    int p = wave & 7;
    int f = lane & 31;
    int b = (p << 1) + (lane >> 5);
    int beg = __builtin_amdgcn_readfirstlane(offs[n]);
    int end = __builtin_amdgcn_readfirstlane(offs[n + 1]);
    int rowbase = b * N;
    float acc = 0.f;
    for (int i = beg; i < end; i++) {
        int s = csrc[i];
        float wn = cnorm[i];
        acc = fmaf(wn, xw1[((rowbase + s) << 5) + f], acc);
    }
    float v = acc + b1[f];
    h1[((rowbase + n) << 5) + f] = fmaxf(v, 0.f);
}

// ---------------- xw2 = h1 @ W2 (W2 stored [32,16]) ----------------
__global__ __launch_bounds__(256) void xw2_kernel(
    const float* __restrict__ h1, const float* __restrict__ W2,
    float* __restrict__ xw2, int BN)
{
    int m = blockIdx.x * 256 + threadIdx.x;
    if (m >= BN) return;
    float hin[32];
    const float4* hp = reinterpret_cast<const float4*>(h1 + (size_t)m * 32);
#pragma unroll
    for (int i = 0; i < 8; i++) {
        float4 v = hp[i];
        hin[4 * i] = v.x; hin[4 * i + 1] = v.y; hin[4 * i + 2] = v.z; hin[4 * i + 3] = v.w;
    }
    float4* op = reinterpret_cast<float4*>(xw2 + (size_t)m * 16);
#pragma unroll
    for (int oc = 0; oc < 4; oc++) {
        float tmp[4];
#pragma unroll
        for (int u = 0; u < 4; u++) {
            int o = oc * 4 + u;
            float a = 0.f;
#pragma unroll
            for (int j = 0; j < 32; j++) a = fmaf(hin[j], W2[j * 16 + o], a);
            tmp[u] = a;
        }
        float4 v; v.x = tmp[0]; v.y = tmp[1]; v.z = tmp[2]; v.w = tmp[3];
        op[oc] = v;
    }
}

// ---------------- conv2 + final linear ----------------
__global__ __launch_bounds__(256) void conv2_kernel(
    const float* __restrict__ xw2, const int* __restrict__ offs,
    const int* __restrict__ csrc, const float* __restrict__ cnorm,
    const float* __restrict__ b2, const float* __restrict__ Wfc,
    const float* __restrict__ bfc, float* __restrict__ out, int N)
{
    int wave = (blockIdx.x << 2) + (threadIdx.x >> 6);
    int lane = threadIdx.x & 63;
    int n = __builtin_amdgcn_readfirstlane(wave >> 2);
    int q = wave & 3;
    int f = lane & 15;
    int b = (q << 2) + (lane >> 4);
    int beg = __builtin_amdgcn_readfirstlane(offs[n]);
    int end = __builtin_amdgcn_readfirstlane(offs[n + 1]);
    float acc = 0.f;
    for (int i = beg; i < end; i++) {
        int s = csrc[i];
        float wn = cnorm[i];
        acc = fmaf(wn, xw2[((b * N + s) << 4) + f], acc);
    }
    float h2 = acc + b2[f];
    float prod = h2 * Wfc[f];
#pragma unroll
    for (int o = 1; o < 16; o <<= 1) prod += __shfl_xor(prod, o, 16);
    if (f == 0) out[b * N + n] = prod + bfc[0];
}

extern "C" void kernel_launch(void* const* d_in, const int* in_sizes, int n_in,
                              void* d_out, int out_size, void* d_ws, size_t ws_size,
                              hipStream_t stream)
{
    const float* x    = (const float*)d_in[0];
    const int*   eidx = (const int*)d_in[1];
    const float* ew   = (const float*)d_in[2];
    const float* w_ih = (const float*)d_in[3];
    const float* w_hh = (const float*)d_in[4];
    const float* b_ih = (const float*)d_in[5];
    const float* b_hh = (const float*)d_in[6];
    const float* W1   = (const float*)d_in[7];
    const float* b1   = (const float*)d_in[8];
    const float* W2   = (const float*)d_in[9];
    const float* b2   = (const float*)d_in[10];
    const float* Wfc  = (const float*)d_in[11];
    const float* bfc  = (const float*)d_in[12];

    const int E  = in_sizes[2];
    const int BN = in_sizes[0] / TLEN;   // 160000
    const int N  = NNODES;               // 10000
    const int* esrc = eidx;
    const int* etgt = eidx + E;
    float* out = (float*)d_out;

    char* w = (char*)d_ws;
    auto alloc = [&](size_t bytes) -> char* {
        char* p = w;
        w += (bytes + 255) / 256 * 256;
        return p;
    };
    float* xw1      = (float*)alloc((size_t)BN * 32 * 4);
    float* h1       = (float*)alloc((size_t)BN * 32 * 4);
    float* xw2      = (float*)alloc((size_t)BN * 16 * 4);
    float* deg      = (float*)alloc((size_t)N * 4);
    float* dinv     = (float*)alloc((size_t)N * 4);
    int*   cnt      = (int*)alloc((size_t)N * 4);
    int*   offs     = (int*)alloc((size_t)(N + 4) * 4);
    int*   cursor   = (int*)alloc((size_t)N * 4);
    int*   csr_src  = (int*)alloc((size_t)(E + N) * 4);
    float* csr_norm = (float*)alloc((size_t)(E + N) * 4);

    hipLaunchKernelGGL(init_deg_cnt, dim3((N + 255) / 256), dim3(256), 0, stream, deg, cnt, N);
    hipLaunchKernelGGL(deg_accum, dim3((E + 255) / 256), dim3(256), 0, stream, esrc, etgt, ew, deg, cnt, E);
    hipLaunchKernelGGL(dinv_kernel, dim3((N + 255) / 256), dim3(256), 0, stream, deg, dinv, N);
    hipLaunchKernelGGL(scan_kernel, dim3(1), dim3(1024), 0, stream, cnt, offs, cursor, N);
    hipLaunchKernelGGL(fill_csr, dim3((E + N + 255) / 256), dim3(256), 0, stream,
                       esrc, etgt, ew, dinv, cursor, csr_src, csr_norm, E, N);

    hipLaunchKernelGGL(gru_xw1_kernel, dim3((BN + 63) / 64), dim3(256), 0, stream,
                       x, w_ih, w_hh, b_ih, b_hh, W1, xw1, BN);
    hipLaunchKernelGGL(conv1_kernel, dim3(N * 2), dim3(256), 0, stream,
                       xw1, offs, csr_src, csr_norm, b1, h1, N);
    hipLaunchKernelGGL(xw2_kernel, dim3((BN + 255) / 256), dim3(256), 0, stream, h1, W2, xw2, BN);
    hipLaunchKernelGGL(conv2_kernel, dim3(N), dim3(256), 0, stream,
                       xw2, offs, csr_src, csr_norm, b2, Wfc, bfc, out, N);
}

// Round 7
// 263.571 us; speedup vs baseline: 4.9260x; 1.1530x over previous
//
#include <hip/hip_runtime.h>

#define TLEN 24
#define HID 32
#define NNODES 10000

typedef __attribute__((ext_vector_type(8))) short short8;
typedef __attribute__((ext_vector_type(4))) float floatx4;
typedef __attribute__((ext_vector_type(4))) int int4v;

__device__ __forceinline__ unsigned short bf16_rne(float f) {
    unsigned u = __float_as_uint(f);
    unsigned r = u + 0x7fffu + ((u >> 16) & 1u);
    return (unsigned short)(r >> 16);
}
__device__ __forceinline__ float bf16_tof(unsigned short b) {
    return __uint_as_float(((unsigned)b) << 16);
}
__device__ __forceinline__ unsigned cvt_pk_bf16(float a, float b) {
    unsigned r;
    asm("v_cvt_pk_bf16_f32 %0, %1, %2" : "=v"(r) : "v"(a), "v"(b));
    return r;  // low16 = bf16(a), high16 = bf16(b)
}
// split pair (a,b) into bf16 hi dword + bf16 lo-residual dword
__device__ __forceinline__ void split_pair(float a, float b, unsigned& hi, unsigned& lo) {
    hi = cvt_pk_bf16(a, b);
    float ar = __uint_as_float(hi << 16);
    float br = __uint_as_float(hi & 0xffff0000u);
    lo = cvt_pk_bf16(a - ar, b - br);
}

#define MFMA16(a, b, c) __builtin_amdgcn_mfma_f32_16x16x32_bf16((a), (b), (c), 0, 0, 0)

// ---------------- GRU via MFMA, 16 seqs per wave (unchanged from R6) ----------------
__global__ __launch_bounds__(256, 3) void gru_xw1_kernel(
    const float* __restrict__ x, const float* __restrict__ w_ih,
    const float* __restrict__ w_hh, const float* __restrict__ b_ih,
    const float* __restrict__ b_hh, const float* __restrict__ W1,
    float* __restrict__ xw1, int BN)
{
    __shared__ float xs[64][25];
    const int tid = threadIdx.x;
    const int wv = tid >> 6, lane = tid & 63;
    const int u = lane >> 4;
    const int s = lane & 15;

    for (int i = tid; i < 64 * TLEN; i += 256) {
        int sl = i / TLEN, t = i - sl * TLEN;
        int gseq = blockIdx.x * 64 + sl;
        if (gseq >= BN) gseq = BN - 1;
        xs[sl][t] = x[(size_t)gseq * TLEN + t];
    }
    __syncthreads();

    const float sc_rz = 1.4426950408889634f;       // log2(e)
    const float sc_n  = 2.8853900817779268f;       // 2*log2(e)

    const int arow_g = 8 * (s >> 2) + (s & 3);
    short8 wh[6], wl[6];
#pragma unroll
    for (int G = 0; G < 3; G++) {
        float sc = (G == 2) ? sc_n : sc_rz;
#pragma unroll
        for (int hf = 0; hf < 2; hf++) {
            int row = G * 32 + arow_g + 4 * hf;
            const float* wp = w_hh + row * 32 + 8 * u;
            unsigned hib[4], lob[4];
#pragma unroll
            for (int p = 0; p < 4; p++)
                split_pair(wp[2 * p] * sc, wp[2 * p + 1] * sc, hib[p], lob[p]);
            int4v hv = {(int)hib[0], (int)hib[1], (int)hib[2], (int)hib[3]};
            int4v lv = {(int)lob[0], (int)lob[1], (int)lob[2], (int)lob[3]};
            wh[G * 2 + hf] = __builtin_bit_cast(short8, hv);
            wl[G * 2 + hf] = __builtin_bit_cast(short8, lv);
        }
    }

    floatx4 CUR[2], CPR[2], CUZ[2], CPZ[2], CUN[2], CBNI[2], CBNH[2];
#pragma unroll
    for (int hf = 0; hf < 2; hf++) {
#pragma unroll
        for (int r = 0; r < 4; r++) {
            int g = 8 * u + hf * 4 + r;
            CUR[hf][r]  = w_ih[g] * sc_rz;
            CPR[hf][r]  = (b_ih[g] + b_hh[g]) * sc_rz;
            CUZ[hf][r]  = w_ih[32 + g] * sc_rz;
            CPZ[hf][r]  = (b_ih[32 + g] + b_hh[32 + g]) * sc_rz;
            CUN[hf][r]  = w_ih[64 + g] * sc_n;
            CBNI[hf][r] = b_ih[64 + g] * sc_n;
            CBNH[hf][r] = b_hh[64 + g] * sc_n;
        }
    }

    asm volatile("" : "+v"(wh[0]), "+v"(wh[1]), "+v"(wh[2]), "+v"(wh[3]),
                      "+v"(wh[4]), "+v"(wh[5]), "+v"(wl[0]), "+v"(wl[1]),
                      "+v"(wl[2]), "+v"(wl[3]), "+v"(wl[4]), "+v"(wl[5]));
    asm volatile("" : "+v"(CUR[0]), "+v"(CUR[1]), "+v"(CPR[0]), "+v"(CPR[1]),
                      "+v"(CUZ[0]), "+v"(CUZ[1]), "+v"(CPZ[0]), "+v"(CPZ[1]));
    asm volatile("" : "+v"(CUN[0]), "+v"(CUN[1]), "+v"(CBNI[0]), "+v"(CBNI[1]),
                      "+v"(CBNH[0]), "+v"(CBNH[1]));

    float h[8];
#pragma unroll
    for (int i = 0; i < 8; i++) h[i] = 0.f;
    short8 Bh = {0, 0, 0, 0, 0, 0, 0, 0}, Bl = {0, 0, 0, 0, 0, 0, 0, 0};

    const int xrow = wv * 16 + s;

#pragma unroll 1
    for (int t = 0; t < TLEN; t++) {
        float xt = xs[xrow][t];
        floatx4 Dr0, Dr1, Dz0, Dz1;
        floatx4 Dn0 = CBNH[0], Dn1 = CBNH[1];
#pragma unroll
        for (int r = 0; r < 4; r++) {
            Dr0[r] = fmaf(xt, CUR[0][r], CPR[0][r]);
            Dr1[r] = fmaf(xt, CUR[1][r], CPR[1][r]);
            Dz0[r] = fmaf(xt, CUZ[0][r], CPZ[0][r]);
            Dz1[r] = fmaf(xt, CUZ[1][r], CPZ[1][r]);
        }
        Dr0 = MFMA16(wh[0], Bh, Dr0); Dr0 = MFMA16(wh[0], Bl, Dr0); Dr0 = MFMA16(wl[0], Bh, Dr0);
        Dr1 = MFMA16(wh[1], Bh, Dr1); Dr1 = MFMA16(wh[1], Bl, Dr1); Dr1 = MFMA16(wl[1], Bh, Dr1);
        Dz0 = MFMA16(wh[2], Bh, Dz0); Dz0 = MFMA16(wh[2], Bl, Dz0); Dz0 = MFMA16(wl[2], Bh, Dz0);
        Dz1 = MFMA16(wh[3], Bh, Dz1); Dz1 = MFMA16(wh[3], Bl, Dz1); Dz1 = MFMA16(wl[3], Bh, Dz1);
        Dn0 = MFMA16(wh[4], Bh, Dn0); Dn0 = MFMA16(wh[4], Bl, Dn0); Dn0 = MFMA16(wl[4], Bh, Dn0);
        Dn1 = MFMA16(wh[5], Bh, Dn1); Dn1 = MFMA16(wh[5], Bl, Dn1); Dn1 = MFMA16(wl[5], Bh, Dn1);

#pragma unroll
        for (int i = 0; i < 8; i++) {
            float dr = (i < 4) ? Dr0[i] : Dr1[i - 4];
            float dz = (i < 4) ? Dz0[i] : Dz1[i - 4];
            float dn = (i < 4) ? Dn0[i] : Dn1[i - 4];
            float rr = __builtin_amdgcn_rcpf(1.f + __builtin_amdgcn_exp2f(-dr));
            float zz = __builtin_amdgcn_rcpf(1.f + __builtin_amdgcn_exp2f(-dz));
            float gxn = fmaf(xt, CUN[i >> 2][i & 3], CBNI[i >> 2][i & 3]);
            float pn2 = fmaf(rr, dn, gxn);
            float e2 = __builtin_amdgcn_exp2f(pn2);
            float tnh = fmaf(-2.f, __builtin_amdgcn_rcpf(e2 + 1.f), 1.f);
            h[i] = fmaf(zz, h[i] - tnh, tnh);
        }
        unsigned hb[4], lb[4];
#pragma unroll
        for (int p = 0; p < 4; p++) split_pair(h[2 * p], h[2 * p + 1], hb[p], lb[p]);
        int4v hv = {(int)hb[0], (int)hb[1], (int)hb[2], (int)hb[3]};
        int4v lv = {(int)lb[0], (int)lb[1], (int)lb[2], (int)lb[3]};
        Bh = __builtin_bit_cast(short8, hv);
        Bl = __builtin_bit_cast(short8, lv);
    }

    short8 W1h[2], W1l[2];
#pragma unroll
    for (int tile = 0; tile < 2; tile++) {
        int o = tile * 16 + s;
        short8 a, b;
#pragma unroll
        for (int j = 0; j < 8; j++) {
            float wfull = W1[(8 * u + j) * 32 + o];
            unsigned short hbb = bf16_rne(wfull);
            float lo = wfull - bf16_tof(hbb);
            a[j] = (short)hbb;
            b[j] = (short)bf16_rne(lo);
        }
        W1h[tile] = a; W1l[tile] = b;
    }
    floatx4 X0, X1;
#pragma unroll
    for (int r = 0; r < 4; r++) { X0[r] = 0.f; X1[r] = 0.f; }
    X0 = MFMA16(W1h[0], Bh, X0); X0 = MFMA16(W1h[0], Bl, X0); X0 = MFMA16(W1l[0], Bh, X0);
    X1 = MFMA16(W1h[1], Bh, X1); X1 = MFMA16(W1h[1], Bl, X1); X1 = MFMA16(W1l[1], Bh, X1);

    int seq = blockIdx.x * 64 + wv * 16 + s;
    if (seq >= BN) seq = BN - 1;
    float4 v0, v1;
    v0.x = X0[0]; v0.y = X0[1]; v0.z = X0[2]; v0.w = X0[3];
    v1.x = X1[0]; v1.y = X1[1]; v1.z = X1[2]; v1.w = X1[3];
    *reinterpret_cast<float4*>(xw1 + (size_t)seq * 32 + 4 * u) = v0;
    *reinterpret_cast<float4*>(xw1 + (size_t)seq * 32 + 16 + 4 * u) = v1;
}

// ---------------- graph prep ----------------
__global__ void init_deg_cnt(float* deg, int* cnt, int N)
{
    int i = blockIdx.x * 256 + threadIdx.x;
    if (i < N) { deg[i] = 1.0f; cnt[i] = 1; }  // self-loop weight 1, one slot
}

__global__ void deg_accum(const int* __restrict__ src, const int* __restrict__ tgt,
                          const float* __restrict__ ew, float* deg, int* cnt, int E)
{
    int e = blockIdx.x * 256 + threadIdx.x;
    if (e < E) {
        int t = tgt[e];
        atomicAdd(&deg[t], ew[e]);
        atomicAdd(&cnt[t], 1);
    }
}

__global__ void dinv_kernel(const float* __restrict__ deg, float* dinv, int N)
{
    int i = blockIdx.x * 256 + threadIdx.x;
    if (i < N) {
        float d = deg[i];
        dinv[i] = d > 0.f ? rsqrtf(d) : 0.f;
    }
}

// single-block one-pass scan: thread owns CH elems, 1024-wide Hillis-Steele
__global__ __launch_bounds__(1024) void scan_kernel(
    const int* __restrict__ cnt, int* offs, int* cursor, int N)
{
    __shared__ int part[1024];
    const int tid = threadIdx.x;
    const int CH = (N + 1023) / 1024;
    const int base = tid * CH;
    int sum = 0;
    for (int k = 0; k < CH; k++) {
        int i = base + k;
        if (i < N) sum += cnt[i];
    }
    part[tid] = sum;
    __syncthreads();
    for (int ofs = 1; ofs < 1024; ofs <<= 1) {
        int v = (tid >= ofs) ? part[tid - ofs] : 0;
        __syncthreads();
        part[tid] += v;
        __syncthreads();
    }
    int run = part[tid] - sum;  // exclusive prefix of this chunk
    if (tid == 0) offs[0] = 0;
    for (int k = 0; k < CH; k++) {
        int i = base + k;
        if (i < N) {
            int c = cnt[i];
            cursor[i] = run;
            run += c;
            offs[i + 1] = run;
        }
    }
}

__global__ void fill_csr(const int* __restrict__ src, const int* __restrict__ tgt,
                         const float* __restrict__ ew, const float* __restrict__ dinv,
                         int* cursor, int* csr_src, float* csr_norm, int E, int N)
{
    int i = blockIdx.x * 256 + threadIdx.x;
    if (i < E) {
        int s = src[i], t = tgt[i];
        int pos = atomicAdd(&cursor[t], 1);
        csr_src[pos] = s;
        csr_norm[pos] = dinv[s] * ew[i] * dinv[t];
    } else if (i < E + N) {
        int n = i - E;
        int pos = atomicAdd(&cursor[n], 1);
        csr_src[pos] = n;
        csr_norm[pos] = dinv[n] * dinv[n];
    }
}

// ---------------- conv1y: y[b,n] = relu(gather(xw1)+b1) . (W2@Wfc) ----------------
// wave = (node, batch-pair); lane = feature(32) x batch-half(2)
__global__ __launch_bounds__(256) void conv1y_kernel(
    const float* __restrict__ xw1, const int* __restrict__ offs,
    const int* __restrict__ csrc, const float* __restrict__ cnorm,
    const float* __restrict__ b1, const float* __restrict__ W2,
    const float* __restrict__ Wfc, float* __restrict__ y, int N)
{
    int wave = (blockIdx.x << 2) + (threadIdx.x >> 6);
    int lane = threadIdx.x & 63;
    int n = __builtin_amdgcn_readfirstlane(wave >> 3);
    int p = wave & 7;
    int f = lane & 31;
    int b = (p << 1) + (lane >> 5);
    // v[f] = sum_o W2[f][o] * Wfc[o]   (W2 stored [32,16])
    float vf = 0.f;
#pragma unroll
    for (int o = 0; o < 16; o++) vf = fmaf(W2[f * 16 + o], Wfc[o], vf);
    float bf = b1[f];
    int beg = __builtin_amdgcn_readfirstlane(offs[n]);
    int end = __builtin_amdgcn_readfirstlane(offs[n + 1]);
    int rowbase = b * N;
    float acc = 0.f;
    for (int i = beg; i < end; i++) {
        int s = csrc[i];
        float wn = cnorm[i];
        acc = fmaf(wn, xw1[((rowbase + s) << 5) + f], acc);
    }
    float val = fmaxf(acc + bf, 0.f) * vf;
#pragma unroll
    for (int m = 1; m < 32; m <<= 1) val += __shfl_xor(val, m);
    if ((lane & 31) == 0) y[rowbase + n] = val;
}

// ---------------- conv2out: out[b,n] = gather-sum(y) + c ----------------
// wave = node; lane = batch(16) x edge-slot(4)
__global__ __launch_bounds__(256) void conv2out_kernel(
    const float* __restrict__ y, const int* __restrict__ offs,
    const int* __restrict__ csrc, const float* __restrict__ cnorm,
    const float* __restrict__ b2, const float* __restrict__ Wfc,
    const float* __restrict__ bfc, float* __restrict__ out, int N)
{
    int wave = (blockIdx.x << 2) + (threadIdx.x >> 6);
    int lane = threadIdx.x & 63;
    int n = __builtin_amdgcn_readfirstlane(wave);
    if (n >= N) return;
    int b = lane & 15, e = lane >> 4;
    float c = bfc[0];
#pragma unroll
    for (int o = 0; o < 16; o++) c = fmaf(b2[o], Wfc[o], c);
    int beg = __builtin_amdgcn_readfirstlane(offs[n]);
    int end = __builtin_amdgcn_readfirstlane(offs[n + 1]);
    float acc = 0.f;
    for (int i = beg + e; i < end; i += 4) {
        int s = csrc[i];
        acc = fmaf(cnorm[i], y[b * N + s], acc);
    }
    acc += __shfl_xor(acc, 16);
    acc += __shfl_xor(acc, 32);
    if (lane < 16) out[b * N + n] = acc + c;
}

extern "C" void kernel_launch(void* const* d_in, const int* in_sizes, int n_in,
                              void* d_out, int out_size, void* d_ws, size_t ws_size,
                              hipStream_t stream)
{
    const float* x    = (const float*)d_in[0];
    const int*   eidx = (const int*)d_in[1];
    const float* ew   = (const float*)d_in[2];
    const float* w_ih = (const float*)d_in[3];
    const float* w_hh = (const float*)d_in[4];
    const float* b_ih = (const float*)d_in[5];
    const float* b_hh = (const float*)d_in[6];
    const float* W1   = (const float*)d_in[7];
    const float* b1   = (const float*)d_in[8];
    const float* W2   = (const float*)d_in[9];
    const float* b2   = (const float*)d_in[10];
    const float* Wfc  = (const float*)d_in[11];
    const float* bfc  = (const float*)d_in[12];

    const int E  = in_sizes[2];
    const int BN = in_sizes[0] / TLEN;   // 160000
    const int N  = NNODES;               // 10000
    const int* esrc = eidx;
    const int* etgt = eidx + E;
    float* out = (float*)d_out;

    char* w = (char*)d_ws;
    auto alloc = [&](size_t bytes) -> char* {
        char* p = w;
        w += (bytes + 255) / 256 * 256;
        return p;
    };
    float* xw1      = (float*)alloc((size_t)BN * 32 * 4);
    float* y        = (float*)alloc((size_t)BN * 4);
    float* deg      = (float*)alloc((size_t)N * 4);
    float* dinv     = (float*)alloc((size_t)N * 4);
    int*   cnt      = (int*)alloc((size_t)N * 4);
    int*   offs     = (int*)alloc((size_t)(N + 4) * 4);
    int*   cursor   = (int*)alloc((size_t)N * 4);
    int*   csr_src  = (int*)alloc((size_t)(E + N) * 4);
    float* csr_norm = (float*)alloc((size_t)(E + N) * 4);

    hipLaunchKernelGGL(init_deg_cnt, dim3((N + 255) / 256), dim3(256), 0, stream, deg, cnt, N);
    hipLaunchKernelGGL(deg_accum, dim3((E + 255) / 256), dim3(256), 0, stream, esrc, etgt, ew, deg, cnt, E);
    hipLaunchKernelGGL(dinv_kernel, dim3((N + 255) / 256), dim3(256), 0, stream, deg, dinv, N);
    hipLaunchKernelGGL(scan_kernel, dim3(1), dim3(1024), 0, stream, cnt, offs, cursor, N);
    hipLaunchKernelGGL(fill_csr, dim3((E + N + 255) / 256), dim3(256), 0, stream,
                       esrc, etgt, ew, dinv, cursor, csr_src, csr_norm, E, N);

    hipLaunchKernelGGL(gru_xw1_kernel, dim3((BN + 63) / 64), dim3(256), 0, stream,
                       x, w_ih, w_hh, b_ih, b_hh, W1, xw1, BN);
    hipLaunchKernelGGL(conv1y_kernel, dim3(N * 2), dim3(256), 0, stream,
                       xw1, offs, csr_src, csr_norm, b1, W2, Wfc, y, N);
    hipLaunchKernelGGL(conv2out_kernel, dim3((N + 3) / 4), dim3(256), 0, stream,
                       y, offs, csr_src, csr_norm, b2, Wfc, bfc, out, N);
}

// Round 8
// 247.758 us; speedup vs baseline: 5.2404x; 1.0638x over previous
//
#include <hip/hip_runtime.h>

#define TLEN 24
#define HID 32
#define NNODES 10000

typedef __attribute__((ext_vector_type(8))) short short8;
typedef __attribute__((ext_vector_type(4))) float floatx4;
typedef __attribute__((ext_vector_type(4))) int int4v;

__device__ __forceinline__ unsigned short bf16_rne(float f) {
    unsigned u = __float_as_uint(f);
    unsigned r = u + 0x7fffu + ((u >> 16) & 1u);
    return (unsigned short)(r >> 16);
}
__device__ __forceinline__ float bf16_tof(unsigned short b) {
    return __uint_as_float(((unsigned)b) << 16);
}
__device__ __forceinline__ unsigned cvt_pk_bf16(float a, float b) {
    unsigned r;
    asm("v_cvt_pk_bf16_f32 %0, %1, %2" : "=v"(r) : "v"(a), "v"(b));
    return r;  // low16 = bf16(a), high16 = bf16(b)
}
// split pair (a,b) into bf16 hi dword + bf16 lo-residual dword
__device__ __forceinline__ void split_pair(float a, float b, unsigned& hi, unsigned& lo) {
    hi = cvt_pk_bf16(a, b);
    float ar = __uint_as_float(hi << 16);
    float br = __uint_as_float(hi & 0xffff0000u);
    lo = cvt_pk_bf16(a - ar, b - br);
}

#define MFMA16(a, b, c) __builtin_amdgcn_mfma_f32_16x16x32_bf16((a), (b), (c), 0, 0, 0)

// ---------------- GRU via MFMA, 16 seqs per wave ----------------
// Epilogue now writes xw1 in [n][b][f] layout (f = conv-gather friendly).
__global__ __launch_bounds__(256, 3) void gru_xw1_kernel(
    const float* __restrict__ x, const float* __restrict__ w_ih,
    const float* __restrict__ w_hh, const float* __restrict__ b_ih,
    const float* __restrict__ b_hh, const float* __restrict__ W1,
    float* __restrict__ xw1, int BN)
{
    __shared__ float xs[64][25];
    const int tid = threadIdx.x;
    const int wv = tid >> 6, lane = tid & 63;
    const int u = lane >> 4;
    const int s = lane & 15;

    for (int i = tid; i < 64 * TLEN; i += 256) {
        int sl = i / TLEN, t = i - sl * TLEN;
        int gseq = blockIdx.x * 64 + sl;
        if (gseq >= BN) gseq = BN - 1;
        xs[sl][t] = x[(size_t)gseq * TLEN + t];
    }
    __syncthreads();

    const float sc_rz = 1.4426950408889634f;       // log2(e)
    const float sc_n  = 2.8853900817779268f;       // 2*log2(e)

    const int arow_g = 8 * (s >> 2) + (s & 3);
    short8 wh[6], wl[6];
#pragma unroll
    for (int G = 0; G < 3; G++) {
        float sc = (G == 2) ? sc_n : sc_rz;
#pragma unroll
        for (int hf = 0; hf < 2; hf++) {
            int row = G * 32 + arow_g + 4 * hf;
            const float* wp = w_hh + row * 32 + 8 * u;
            unsigned hib[4], lob[4];
#pragma unroll
            for (int p = 0; p < 4; p++)
                split_pair(wp[2 * p] * sc, wp[2 * p + 1] * sc, hib[p], lob[p]);
            int4v hv = {(int)hib[0], (int)hib[1], (int)hib[2], (int)hib[3]};
            int4v lv = {(int)lob[0], (int)lob[1], (int)lob[2], (int)lob[3]};
            wh[G * 2 + hf] = __builtin_bit_cast(short8, hv);
            wl[G * 2 + hf] = __builtin_bit_cast(short8, lv);
        }
    }

    floatx4 CUR[2], CPR[2], CUZ[2], CPZ[2], CUN[2], CBNI[2], CBNH[2];
#pragma unroll
    for (int hf = 0; hf < 2; hf++) {
#pragma unroll
        for (int r = 0; r < 4; r++) {
            int g = 8 * u + hf * 4 + r;
            CUR[hf][r]  = w_ih[g] * sc_rz;
            CPR[hf][r]  = (b_ih[g] + b_hh[g]) * sc_rz;
            CUZ[hf][r]  = w_ih[32 + g] * sc_rz;
            CPZ[hf][r]  = (b_ih[32 + g] + b_hh[32 + g]) * sc_rz;
            CUN[hf][r]  = w_ih[64 + g] * sc_n;
            CBNI[hf][r] = b_ih[64 + g] * sc_n;
            CBNH[hf][r] = b_hh[64 + g] * sc_n;
        }
    }

    asm volatile("" : "+v"(wh[0]), "+v"(wh[1]), "+v"(wh[2]), "+v"(wh[3]),
                      "+v"(wh[4]), "+v"(wh[5]), "+v"(wl[0]), "+v"(wl[1]),
                      "+v"(wl[2]), "+v"(wl[3]), "+v"(wl[4]), "+v"(wl[5]));
    asm volatile("" : "+v"(CUR[0]), "+v"(CUR[1]), "+v"(CPR[0]), "+v"(CPR[1]),
                      "+v"(CUZ[0]), "+v"(CUZ[1]), "+v"(CPZ[0]), "+v"(CPZ[1]));
    asm volatile("" : "+v"(CUN[0]), "+v"(CUN[1]), "+v"(CBNI[0]), "+v"(CBNI[1]),
                      "+v"(CBNH[0]), "+v"(CBNH[1]));

    float h[8];
#pragma unroll
    for (int i = 0; i < 8; i++) h[i] = 0.f;
    short8 Bh = {0, 0, 0, 0, 0, 0, 0, 0}, Bl = {0, 0, 0, 0, 0, 0, 0, 0};

    const int xrow = wv * 16 + s;

#pragma unroll 1
    for (int t = 0; t < TLEN; t++) {
        float xt = xs[xrow][t];
        floatx4 Dr0, Dr1, Dz0, Dz1;
        floatx4 Dn0 = CBNH[0], Dn1 = CBNH[1];
#pragma unroll
        for (int r = 0; r < 4; r++) {
            Dr0[r] = fmaf(xt, CUR[0][r], CPR[0][r]);
            Dr1[r] = fmaf(xt, CUR[1][r], CPR[1][r]);
            Dz0[r] = fmaf(xt, CUZ[0][r], CPZ[0][r]);
            Dz1[r] = fmaf(xt, CUZ[1][r], CPZ[1][r]);
        }
        Dr0 = MFMA16(wh[0], Bh, Dr0); Dr0 = MFMA16(wh[0], Bl, Dr0); Dr0 = MFMA16(wl[0], Bh, Dr0);
        Dr1 = MFMA16(wh[1], Bh, Dr1); Dr1 = MFMA16(wh[1], Bl, Dr1); Dr1 = MFMA16(wl[1], Bh, Dr1);
        Dz0 = MFMA16(wh[2], Bh, Dz0); Dz0 = MFMA16(wh[2], Bl, Dz0); Dz0 = MFMA16(wl[2], Bh, Dz0);
        Dz1 = MFMA16(wh[3], Bh, Dz1); Dz1 = MFMA16(wh[3], Bl, Dz1); Dz1 = MFMA16(wl[3], Bh, Dz1);
        Dn0 = MFMA16(wh[4], Bh, Dn0); Dn0 = MFMA16(wh[4], Bl, Dn0); Dn0 = MFMA16(wl[4], Bh, Dn0);
        Dn1 = MFMA16(wh[5], Bh, Dn1); Dn1 = MFMA16(wh[5], Bl, Dn1); Dn1 = MFMA16(wl[5], Bh, Dn1);

#pragma unroll
        for (int i = 0; i < 8; i++) {
            float dr = (i < 4) ? Dr0[i] : Dr1[i - 4];
            float dz = (i < 4) ? Dz0[i] : Dz1[i - 4];
            float dn = (i < 4) ? Dn0[i] : Dn1[i - 4];
            float rr = __builtin_amdgcn_rcpf(1.f + __builtin_amdgcn_exp2f(-dr));
            float zz = __builtin_amdgcn_rcpf(1.f + __builtin_amdgcn_exp2f(-dz));
            float gxn = fmaf(xt, CUN[i >> 2][i & 3], CBNI[i >> 2][i & 3]);
            float pn2 = fmaf(rr, dn, gxn);
            float e2 = __builtin_amdgcn_exp2f(pn2);
            float tnh = fmaf(-2.f, __builtin_amdgcn_rcpf(e2 + 1.f), 1.f);
            h[i] = fmaf(zz, h[i] - tnh, tnh);
        }
        unsigned hb[4], lb[4];
#pragma unroll
        for (int p = 0; p < 4; p++) split_pair(h[2 * p], h[2 * p + 1], hb[p], lb[p]);
        int4v hv = {(int)hb[0], (int)hb[1], (int)hb[2], (int)hb[3]};
        int4v lv = {(int)lb[0], (int)lb[1], (int)lb[2], (int)lb[3]};
        Bh = __builtin_bit_cast(short8, hv);
        Bl = __builtin_bit_cast(short8, lv);
    }

    short8 W1h[2], W1l[2];
#pragma unroll
    for (int tile = 0; tile < 2; tile++) {
        int o = tile * 16 + s;
        short8 a, b;
#pragma unroll
        for (int j = 0; j < 8; j++) {
            float wfull = W1[(8 * u + j) * 32 + o];
            unsigned short hbb = bf16_rne(wfull);
            float lo = wfull - bf16_tof(hbb);
            a[j] = (short)hbb;
            b[j] = (short)bf16_rne(lo);
        }
        W1h[tile] = a; W1l[tile] = b;
    }
    floatx4 X0, X1;
#pragma unroll
    for (int r = 0; r < 4; r++) { X0[r] = 0.f; X1[r] = 0.f; }
    X0 = MFMA16(W1h[0], Bh, X0); X0 = MFMA16(W1h[0], Bl, X0); X0 = MFMA16(W1l[0], Bh, X0);
    X1 = MFMA16(W1h[1], Bh, X1); X1 = MFMA16(W1h[1], Bl, X1); X1 = MFMA16(W1l[1], Bh, X1);

    int seq = blockIdx.x * 64 + wv * 16 + s;
    if (seq >= BN) seq = BN - 1;
    // xw1 layout: [n][b][f] (f contiguous); seq = b*N + n
    int bq = seq / NNODES;
    int nn = seq - bq * NNODES;
    float* base = xw1 + (size_t)nn * 512 + bq * 32 + 4 * u;
    float4 v0, v1;
    v0.x = X0[0]; v0.y = X0[1]; v0.z = X0[2]; v0.w = X0[3];
    v1.x = X1[0]; v1.y = X1[1]; v1.z = X1[2]; v1.w = X1[3];
    *reinterpret_cast<float4*>(base) = v0;
    *reinterpret_cast<float4*>(base + 16) = v1;
}

// ---------------- graph prep ----------------
__global__ void init_deg_cnt(float* deg, int* cnt, int N)
{
    int i = blockIdx.x * 256 + threadIdx.x;
    if (i < N) { deg[i] = 1.0f; cnt[i] = 1; }  // self-loop weight 1, one slot
}

__global__ void deg_accum(const int* __restrict__ src, const int* __restrict__ tgt,
                          const float* __restrict__ ew, float* deg, int* cnt, int E)
{
    int e = blockIdx.x * 256 + threadIdx.x;
    if (e < E) {
        int t = tgt[e];
        atomicAdd(&deg[t], ew[e]);
        atomicAdd(&cnt[t], 1);
    }
}

__global__ void dinv_kernel(const float* __restrict__ deg, float* dinv, int N)
{
    int i = blockIdx.x * 256 + threadIdx.x;
    if (i < N) {
        float d = deg[i];
        dinv[i] = d > 0.f ? rsqrtf(d) : 0.f;
    }
}

// single-block one-pass scan: thread owns CH elems, 1024-wide Hillis-Steele
__global__ __launch_bounds__(1024) void scan_kernel(
    const int* __restrict__ cnt, int* offs, int* cursor, int N)
{
    __shared__ int part[1024];
    const int tid = threadIdx.x;
    const int CH = (N + 1023) / 1024;
    const int base = tid * CH;
    int sum = 0;
    for (int k = 0; k < CH; k++) {
        int i = base + k;
        if (i < N) sum += cnt[i];
    }
    part[tid] = sum;
    __syncthreads();
    for (int ofs = 1; ofs < 1024; ofs <<= 1) {
        int v = (tid >= ofs) ? part[tid - ofs] : 0;
        __syncthreads();
        part[tid] += v;
        __syncthreads();
    }
    int run = part[tid] - sum;  // exclusive prefix of this chunk
    if (tid == 0) offs[0] = 0;
    for (int k = 0; k < CH; k++) {
        int i = base + k;
        if (i < N) {
            int c = cnt[i];
            cursor[i] = run;
            run += c;
            offs[i + 1] = run;
        }
    }
}

__global__ void fill_csr(const int* __restrict__ src, const int* __restrict__ tgt,
                         const float* __restrict__ ew, const float* __restrict__ dinv,
                         int* cursor, int* csr_src, float* csr_norm, int E, int N)
{
    int i = blockIdx.x * 256 + threadIdx.x;
    if (i < E) {
        int s = src[i], t = tgt[i];
        int pos = atomicAdd(&cursor[t], 1);
        csr_src[pos] = s;
        csr_norm[pos] = dinv[s] * ew[i] * dinv[t];
    } else if (i < E + N) {
        int n = i - E;
        int pos = atomicAdd(&cursor[n], 1);
        csr_src[pos] = n;
        csr_norm[pos] = dinv[n] * dinv[n];
    }
}

// ---------------- conv1y: y[n][b] = relu(gather(xw1)+b1) . (W2@Wfc) ----------------
// one wave per node; lane = (b = lane>>2, f4 = lane&3); per-lane 8 features.
// Per edge: 2 coalesced float4 wave-loads (the node's full 2KB [16][32] tile).
__global__ __launch_bounds__(256) void conv1y_kernel(
    const float* __restrict__ xw1, const int* __restrict__ offs,
    const int* __restrict__ csrc, const float* __restrict__ cnorm,
    const float* __restrict__ b1, const float* __restrict__ W2,
    const float* __restrict__ Wfc, float* __restrict__ y, int N)
{
    int n = __builtin_amdgcn_readfirstlane((blockIdx.x << 2) + (threadIdx.x >> 6));
    if (n >= N) return;
    int lane = threadIdx.x & 63;
    int b = lane >> 2, f4 = lane & 3;

    // vf[j] = sum_o W2[f][o]*Wfc[o], bf[j] = b1[f], f = f4*8+j
    float vf[8], bf[8];
#pragma unroll
    for (int j = 0; j < 8; j++) {
        int f = f4 * 8 + j;
        float a = 0.f;
#pragma unroll
        for (int o = 0; o < 16; o++) a = fmaf(W2[f * 16 + o], Wfc[o], a);
        vf[j] = a;
        bf[j] = b1[f];
    }

    int beg = __builtin_amdgcn_readfirstlane(offs[n]);
    int end = __builtin_amdgcn_readfirstlane(offs[n + 1]);
    float acc[8];
#pragma unroll
    for (int j = 0; j < 8; j++) acc[j] = 0.f;

    for (int i = beg; i < end; i++) {
        int s = csrc[i];
        float wn = cnorm[i];
        const float4* p = reinterpret_cast<const float4*>(xw1 + (size_t)s * 512 + lane * 8);
        float4 v0 = p[0], v1 = p[1];
        acc[0] = fmaf(wn, v0.x, acc[0]);
        acc[1] = fmaf(wn, v0.y, acc[1]);
        acc[2] = fmaf(wn, v0.z, acc[2]);
        acc[3] = fmaf(wn, v0.w, acc[3]);
        acc[4] = fmaf(wn, v1.x, acc[4]);
        acc[5] = fmaf(wn, v1.y, acc[5]);
        acc[6] = fmaf(wn, v1.z, acc[6]);
        acc[7] = fmaf(wn, v1.w, acc[7]);
    }

    float val = 0.f;
#pragma unroll
    for (int j = 0; j < 8; j++)
        val = fmaf(fmaxf(acc[j] + bf[j], 0.f), vf[j], val);
    val += __shfl_xor(val, 1);
    val += __shfl_xor(val, 2);
    if (f4 == 0) y[n * 16 + b] = val;
}

// ---------------- conv2out: out[b,n] = gather-sum(y) + c ----------------
// wave = node; lane = batch(16) x edge-slot(4); y gathers are 64B lines.
__global__ __launch_bounds__(256) void conv2out_kernel(
    const float* __restrict__ y, const int* __restrict__ offs,
    const int* __restrict__ csrc, const float* __restrict__ cnorm,
    const float* __restrict__ b2, const float* __restrict__ Wfc,
    const float* __restrict__ bfc, float* __restrict__ out, int N)
{
    int n = __builtin_amdgcn_readfirstlane((blockIdx.x << 2) + (threadIdx.x >> 6));
    if (n >= N) return;
    int lane = threadIdx.x & 63;
    int b = lane & 15, e = lane >> 4;
    float c = bfc[0];
#pragma unroll
    for (int o = 0; o < 16; o++) c = fmaf(b2[o], Wfc[o], c);
    int beg = __builtin_amdgcn_readfirstlane(offs[n]);
    int end = __builtin_amdgcn_readfirstlane(offs[n + 1]);
    float acc = 0.f;
    for (int i = beg + e; i < end; i += 4) {
        int s = csrc[i];
        acc = fmaf(cnorm[i], y[s * 16 + b], acc);
    }
    acc += __shfl_xor(acc, 16);
    acc += __shfl_xor(acc, 32);
    if (lane < 16) out[b * N + n] = acc + c;
}

extern "C" void kernel_launch(void* const* d_in, const int* in_sizes, int n_in,
                              void* d_out, int out_size, void* d_ws, size_t ws_size,
                              hipStream_t stream)
{
    const float* x    = (const float*)d_in[0];
    const int*   eidx = (const int*)d_in[1];
    const float* ew   = (const float*)d_in[2];
    const float* w_ih = (const float*)d_in[3];
    const float* w_hh = (const float*)d_in[4];
    const float* b_ih = (const float*)d_in[5];
    const float* b_hh = (const float*)d_in[6];
    const float* W1   = (const float*)d_in[7];
    const float* b1   = (const float*)d_in[8];
    const float* W2   = (const float*)d_in[9];
    const float* b2   = (const float*)d_in[10];
    const float* Wfc  = (const float*)d_in[11];
    const float* bfc  = (const float*)d_in[12];

    const int E  = in_sizes[2];
    const int BN = in_sizes[0] / TLEN;   // 160000
    const int N  = NNODES;               // 10000
    const int* esrc = eidx;
    const int* etgt = eidx + E;
    float* out = (float*)d_out;

    char* w = (char*)d_ws;
    auto alloc = [&](size_t bytes) -> char* {
        char* p = w;
        w += (bytes + 255) / 256 * 256;
        return p;
    };
    float* xw1      = (float*)alloc((size_t)BN * 32 * 4);   // [n][16][32]
    float* y        = (float*)alloc((size_t)N * 16 * 4);    // [n][16]
    float* deg      = (float*)alloc((size_t)N * 4);
    float* dinv     = (float*)alloc((size_t)N * 4);
    int*   cnt      = (int*)alloc((size_t)N * 4);
    int*   offs     = (int*)alloc((size_t)(N + 4) * 4);
    int*   cursor   = (int*)alloc((size_t)N * 4);
    int*   csr_src  = (int*)alloc((size_t)(E + N) * 4);
    float* csr_norm = (float*)alloc((size_t)(E + N) * 4);

    hipLaunchKernelGGL(init_deg_cnt, dim3((N + 255) / 256), dim3(256), 0, stream, deg, cnt, N);
    hipLaunchKernelGGL(deg_accum, dim3((E + 255) / 256), dim3(256), 0, stream, esrc, etgt, ew, deg, cnt, E);
    hipLaunchKernelGGL(dinv_kernel, dim3((N + 255) / 256), dim3(256), 0, stream, deg, dinv, N);
    hipLaunchKernelGGL(scan_kernel, dim3(1), dim3(1024), 0, stream, cnt, offs, cursor, N);
    hipLaunchKernelGGL(fill_csr, dim3((E + N + 255) / 256), dim3(256), 0, stream,
                       esrc, etgt, ew, dinv, cursor, csr_src, csr_norm, E, N);

    hipLaunchKernelGGL(gru_xw1_kernel, dim3((BN + 63) / 64), dim3(256), 0, stream,
                       x, w_ih, w_hh, b_ih, b_hh, W1, xw1, BN);
    hipLaunchKernelGGL(conv1y_kernel, dim3((N + 3) / 4), dim3(256), 0, stream,
                       xw1, offs, csr_src, csr_norm, b1, W2, Wfc, y, N);
    hipLaunchKernelGGL(conv2out_kernel, dim3((N + 3) / 4), dim3(256), 0, stream,
                       y, offs, csr_src, csr_norm, b2, Wfc, bfc, out, N);
}

// Round 9
// 244.401 us; speedup vs baseline: 5.3124x; 1.0137x over previous
//
#include <hip/hip_runtime.h>

#define TLEN 24
#define HID 32
#define NNODES 10000

typedef __attribute__((ext_vector_type(8))) short short8;
typedef __attribute__((ext_vector_type(4))) float floatx4;
typedef __attribute__((ext_vector_type(4))) int int4v;
typedef __attribute__((ext_vector_type(4))) _Float16 half4;
typedef __attribute__((ext_vector_type(8))) _Float16 half8;

__device__ __forceinline__ unsigned short bf16_rne(float f) {
    unsigned u = __float_as_uint(f);
    unsigned r = u + 0x7fffu + ((u >> 16) & 1u);
    return (unsigned short)(r >> 16);
}
__device__ __forceinline__ float bf16_tof(unsigned short b) {
    return __uint_as_float(((unsigned)b) << 16);
}
__device__ __forceinline__ unsigned cvt_pk_bf16(float a, float b) {
    unsigned r;
    asm("v_cvt_pk_bf16_f32 %0, %1, %2" : "=v"(r) : "v"(a), "v"(b));
    return r;  // low16 = bf16(a), high16 = bf16(b)
}
// split pair (a,b) into bf16 hi dword + bf16 lo-residual dword
__device__ __forceinline__ void split_pair(float a, float b, unsigned& hi, unsigned& lo) {
    hi = cvt_pk_bf16(a, b);
    float ar = __uint_as_float(hi << 16);
    float br = __uint_as_float(hi & 0xffff0000u);
    lo = cvt_pk_bf16(a - ar, b - br);
}

#define MFMA16(a, b, c) __builtin_amdgcn_mfma_f32_16x16x32_bf16((a), (b), (c), 0, 0, 0)

// ---------------- GRU via MFMA, 16 seqs per wave ----------------
// Epilogue writes xw1 as fp16 in [n][b][f] layout (1KB per node tile).
__global__ __launch_bounds__(256, 3) void gru_xw1_kernel(
    const float* __restrict__ x, const float* __restrict__ w_ih,
    const float* __restrict__ w_hh, const float* __restrict__ b_ih,
    const float* __restrict__ b_hh, const float* __restrict__ W1,
    _Float16* __restrict__ xw1, int BN)
{
    __shared__ float xs[64][25];
    const int tid = threadIdx.x;
    const int wv = tid >> 6, lane = tid & 63;
    const int u = lane >> 4;
    const int s = lane & 15;

    for (int i = tid; i < 64 * TLEN; i += 256) {
        int sl = i / TLEN, t = i - sl * TLEN;
        int gseq = blockIdx.x * 64 + sl;
        if (gseq >= BN) gseq = BN - 1;
        xs[sl][t] = x[(size_t)gseq * TLEN + t];
    }
    __syncthreads();

    const float sc_rz = 1.4426950408889634f;       // log2(e)
    const float sc_n  = 2.8853900817779268f;       // 2*log2(e)

    const int arow_g = 8 * (s >> 2) + (s & 3);
    short8 wh[6], wl[6];
#pragma unroll
    for (int G = 0; G < 3; G++) {
        float sc = (G == 2) ? sc_n : sc_rz;
#pragma unroll
        for (int hf = 0; hf < 2; hf++) {
            int row = G * 32 + arow_g + 4 * hf;
            const float* wp = w_hh + row * 32 + 8 * u;
            unsigned hib[4], lob[4];
#pragma unroll
            for (int p = 0; p < 4; p++)
                split_pair(wp[2 * p] * sc, wp[2 * p + 1] * sc, hib[p], lob[p]);
            int4v hv = {(int)hib[0], (int)hib[1], (int)hib[2], (int)hib[3]};
            int4v lv = {(int)lob[0], (int)lob[1], (int)lob[2], (int)lob[3]};
            wh[G * 2 + hf] = __builtin_bit_cast(short8, hv);
            wl[G * 2 + hf] = __builtin_bit_cast(short8, lv);
        }
    }

    floatx4 CUR[2], CPR[2], CUZ[2], CPZ[2], CUN[2], CBNI[2], CBNH[2];
#pragma unroll
    for (int hf = 0; hf < 2; hf++) {
#pragma unroll
        for (int r = 0; r < 4; r++) {
            int g = 8 * u + hf * 4 + r;
            CUR[hf][r]  = w_ih[g] * sc_rz;
            CPR[hf][r]  = (b_ih[g] + b_hh[g]) * sc_rz;
            CUZ[hf][r]  = w_ih[32 + g] * sc_rz;
            CPZ[hf][r]  = (b_ih[32 + g] + b_hh[32 + g]) * sc_rz;
            CUN[hf][r]  = w_ih[64 + g] * sc_n;
            CBNI[hf][r] = b_ih[64 + g] * sc_n;
            CBNH[hf][r] = b_hh[64 + g] * sc_n;
        }
    }

    asm volatile("" : "+v"(wh[0]), "+v"(wh[1]), "+v"(wh[2]), "+v"(wh[3]),
                      "+v"(wh[4]), "+v"(wh[5]), "+v"(wl[0]), "+v"(wl[1]),
                      "+v"(wl[2]), "+v"(wl[3]), "+v"(wl[4]), "+v"(wl[5]));
    asm volatile("" : "+v"(CUR[0]), "+v"(CUR[1]), "+v"(CPR[0]), "+v"(CPR[1]),
                      "+v"(CUZ[0]), "+v"(CUZ[1]), "+v"(CPZ[0]), "+v"(CPZ[1]));
    asm volatile("" : "+v"(CUN[0]), "+v"(CUN[1]), "+v"(CBNI[0]), "+v"(CBNI[1]),
                      "+v"(CBNH[0]), "+v"(CBNH[1]));

    float h[8];
#pragma unroll
    for (int i = 0; i < 8; i++) h[i] = 0.f;
    short8 Bh = {0, 0, 0, 0, 0, 0, 0, 0}, Bl = {0, 0, 0, 0, 0, 0, 0, 0};

    const int xrow = wv * 16 + s;

#pragma unroll 1
    for (int t = 0; t < TLEN; t++) {
        float xt = xs[xrow][t];
        floatx4 Dr0, Dr1, Dz0, Dz1;
        floatx4 Dn0 = CBNH[0], Dn1 = CBNH[1];
#pragma unroll
        for (int r = 0; r < 4; r++) {
            Dr0[r] = fmaf(xt, CUR[0][r], CPR[0][r]);
            Dr1[r] = fmaf(xt, CUR[1][r], CPR[1][r]);
            Dz0[r] = fmaf(xt, CUZ[0][r], CPZ[0][r]);
            Dz1[r] = fmaf(xt, CUZ[1][r], CPZ[1][r]);
        }
        Dr0 = MFMA16(wh[0], Bh, Dr0); Dr0 = MFMA16(wh[0], Bl, Dr0); Dr0 = MFMA16(wl[0], Bh, Dr0);
        Dr1 = MFMA16(wh[1], Bh, Dr1); Dr1 = MFMA16(wh[1], Bl, Dr1); Dr1 = MFMA16(wl[1], Bh, Dr1);
        Dz0 = MFMA16(wh[2], Bh, Dz0); Dz0 = MFMA16(wh[2], Bl, Dz0); Dz0 = MFMA16(wl[2], Bh, Dz0);
        Dz1 = MFMA16(wh[3], Bh, Dz1); Dz1 = MFMA16(wh[3], Bl, Dz1); Dz1 = MFMA16(wl[3], Bh, Dz1);
        Dn0 = MFMA16(wh[4], Bh, Dn0); Dn0 = MFMA16(wh[4], Bl, Dn0); Dn0 = MFMA16(wl[4], Bh, Dn0);
        Dn1 = MFMA16(wh[5], Bh, Dn1); Dn1 = MFMA16(wh[5], Bl, Dn1); Dn1 = MFMA16(wl[5], Bh, Dn1);

#pragma unroll
        for (int i = 0; i < 8; i++) {
            float dr = (i < 4) ? Dr0[i] : Dr1[i - 4];
            float dz = (i < 4) ? Dz0[i] : Dz1[i - 4];
            float dn = (i < 4) ? Dn0[i] : Dn1[i - 4];
            float rr = __builtin_amdgcn_rcpf(1.f + __builtin_amdgcn_exp2f(-dr));
            float zz = __builtin_amdgcn_rcpf(1.f + __builtin_amdgcn_exp2f(-dz));
            float gxn = fmaf(xt, CUN[i >> 2][i & 3], CBNI[i >> 2][i & 3]);
            float pn2 = fmaf(rr, dn, gxn);
            float e2 = __builtin_amdgcn_exp2f(pn2);
            float tnh = fmaf(-2.f, __builtin_amdgcn_rcpf(e2 + 1.f), 1.f);
            h[i] = fmaf(zz, h[i] - tnh, tnh);
        }
        unsigned hb[4], lb[4];
#pragma unroll
        for (int p = 0; p < 4; p++) split_pair(h[2 * p], h[2 * p + 1], hb[p], lb[p]);
        int4v hv = {(int)hb[0], (int)hb[1], (int)hb[2], (int)hb[3]};
        int4v lv = {(int)lb[0], (int)lb[1], (int)lb[2], (int)lb[3]};
        Bh = __builtin_bit_cast(short8, hv);
        Bl = __builtin_bit_cast(short8, lv);
    }

    short8 W1h[2], W1l[2];
#pragma unroll
    for (int tile = 0; tile < 2; tile++) {
        int o = tile * 16 + s;
        short8 a, b;
#pragma unroll
        for (int j = 0; j < 8; j++) {
            float wfull = W1[(8 * u + j) * 32 + o];
            unsigned short hbb = bf16_rne(wfull);
            float lo = wfull - bf16_tof(hbb);
            a[j] = (short)hbb;
            b[j] = (short)bf16_rne(lo);
        }
        W1h[tile] = a; W1l[tile] = b;
    }
    floatx4 X0, X1;
#pragma unroll
    for (int r = 0; r < 4; r++) { X0[r] = 0.f; X1[r] = 0.f; }
    X0 = MFMA16(W1h[0], Bh, X0); X0 = MFMA16(W1h[0], Bl, X0); X0 = MFMA16(W1l[0], Bh, X0);
    X1 = MFMA16(W1h[1], Bh, X1); X1 = MFMA16(W1h[1], Bl, X1); X1 = MFMA16(W1l[1], Bh, X1);

    int seq = blockIdx.x * 64 + wv * 16 + s;
    if (seq >= BN) seq = BN - 1;
    // xw1 layout: [n][b][f] fp16; seq = b*N + n
    int bq = seq / NNODES;
    int nn = seq - bq * NNODES;
    _Float16* base = xw1 + (size_t)nn * 512 + bq * 32 + 4 * u;
    half4 o0, o1;
#pragma unroll
    for (int r = 0; r < 4; r++) { o0[r] = (_Float16)X0[r]; o1[r] = (_Float16)X1[r]; }
    *reinterpret_cast<half4*>(base) = o0;
    *reinterpret_cast<half4*>(base + 16) = o1;
}

// ---------------- graph prep ----------------
__global__ void init_deg_cnt(float* deg, int* cnt, int N)
{
    int i = blockIdx.x * 256 + threadIdx.x;
    if (i < N) { deg[i] = 1.0f; cnt[i] = 1; }  // self-loop weight 1, one slot
}

__global__ void deg_accum(const int* __restrict__ src, const int* __restrict__ tgt,
                          const float* __restrict__ ew, float* deg, int* cnt, int E)
{
    int e = blockIdx.x * 256 + threadIdx.x;
    if (e < E) {
        int t = tgt[e];
        atomicAdd(&deg[t], ew[e]);
        atomicAdd(&cnt[t], 1);
    }
}

// single-block one-pass scan + dinv: thread owns CH elems
__global__ __launch_bounds__(1024) void scan_kernel(
    const int* __restrict__ cnt, const float* __restrict__ deg,
    float* __restrict__ dinv, int* offs, int* cursor, int N)
{
    __shared__ int part[1024];
    const int tid = threadIdx.x;
    const int CH = (N + 1023) / 1024;
    const int base = tid * CH;
    int sum = 0;
    for (int k = 0; k < CH; k++) {
        int i = base + k;
        if (i < N) {
            sum += cnt[i];
            float d = deg[i];
            dinv[i] = d > 0.f ? __frsqrt_rn(d) : 0.f;
        }
    }
    part[tid] = sum;
    __syncthreads();
    for (int ofs = 1; ofs < 1024; ofs <<= 1) {
        int v = (tid >= ofs) ? part[tid - ofs] : 0;
        __syncthreads();
        part[tid] += v;
        __syncthreads();
    }
    int run = part[tid] - sum;  // exclusive prefix of this chunk
    if (tid == 0) offs[0] = 0;
    for (int k = 0; k < CH; k++) {
        int i = base + k;
        if (i < N) {
            int c = cnt[i];
            cursor[i] = run;
            run += c;
            offs[i + 1] = run;
        }
    }
}

__global__ void fill_csr(const int* __restrict__ src, const int* __restrict__ tgt,
                         const float* __restrict__ ew, const float* __restrict__ dinv,
                         int* cursor, int* csr_src, float* csr_norm, int E, int N)
{
    int i = blockIdx.x * 256 + threadIdx.x;
    if (i < E) {
        int s = src[i], t = tgt[i];
        int pos = atomicAdd(&cursor[t], 1);
        csr_src[pos] = s;
        csr_norm[pos] = dinv[s] * ew[i] * dinv[t];
    } else if (i < E + N) {
        int n = i - E;
        int pos = atomicAdd(&cursor[n], 1);
        csr_src[pos] = n;
        csr_norm[pos] = dinv[n] * dinv[n];
    }
}

// ---------------- conv1y: y[n][b] = relu(gather(xw1)+b1) . (W2@Wfc) ----------------
// one wave per node; lane = (b = lane>>2, f4 = lane&3); per-lane 8 fp16 features
// = one 16B load per edge (wave reads the node's full 1KB tile, coalesced).
// Edge loop is 2-stage software-pipelined.
__global__ __launch_bounds__(256) void conv1y_kernel(
    const _Float16* __restrict__ xw1, const int* __restrict__ offs,
    const int* __restrict__ csrc, const float* __restrict__ cnorm,
    const float* __restrict__ b1, const float* __restrict__ W2,
    const float* __restrict__ Wfc, float* __restrict__ y, int N)
{
    int n = __builtin_amdgcn_readfirstlane((blockIdx.x << 2) + (threadIdx.x >> 6));
    if (n >= N) return;
    int lane = threadIdx.x & 63;
    int b = lane >> 2, f4 = lane & 3;

    // vf[j] = sum_o W2[f][o]*Wfc[o], bf[j] = b1[f], f = f4*8+j
    float vf[8], bf[8];
#pragma unroll
    for (int j = 0; j < 8; j++) {
        int f = f4 * 8 + j;
        float a = 0.f;
#pragma unroll
        for (int o = 0; o < 16; o++) a = fmaf(W2[f * 16 + o], Wfc[o], a);
        vf[j] = a;
        bf[j] = b1[f];
    }

    int beg = __builtin_amdgcn_readfirstlane(offs[n]);
    int end = __builtin_amdgcn_readfirstlane(offs[n + 1]);
    float acc[8];
#pragma unroll
    for (int j = 0; j < 8; j++) acc[j] = 0.f;

    // 2-stage pipeline (deg >= 1 always: self-loop)
    float wcur = cnorm[beg];
    half8 vcur = *reinterpret_cast<const half8*>(xw1 + (size_t)csrc[beg] * 512 + lane * 8);
    for (int i = beg; i < end; i++) {
        float wnext = 0.f;
        half8 vnext = vcur;
        if (i + 1 < end) {
            wnext = cnorm[i + 1];
            vnext = *reinterpret_cast<const half8*>(xw1 + (size_t)csrc[i + 1] * 512 + lane * 8);
        }
#pragma unroll
        for (int j = 0; j < 8; j++) acc[j] = fmaf(wcur, (float)vcur[j], acc[j]);
        wcur = wnext;
        vcur = vnext;
    }

    float val = 0.f;
#pragma unroll
    for (int j = 0; j < 8; j++)
        val = fmaf(fmaxf(acc[j] + bf[j], 0.f), vf[j], val);
    val += __shfl_xor(val, 1);
    val += __shfl_xor(val, 2);
    if (f4 == 0) y[n * 16 + b] = val;
}

// ---------------- conv2out: out[b,n] = gather-sum(y) + c ----------------
// wave = node; lane = batch(16) x edge-slot(4); y gathers are 64B lines.
__global__ __launch_bounds__(256) void conv2out_kernel(
    const float* __restrict__ y, const int* __restrict__ offs,
    const int* __restrict__ csrc, const float* __restrict__ cnorm,
    const float* __restrict__ b2, const float* __restrict__ Wfc,
    const float* __restrict__ bfc, float* __restrict__ out, int N)
{
    int n = __builtin_amdgcn_readfirstlane((blockIdx.x << 2) + (threadIdx.x >> 6));
    if (n >= N) return;
    int lane = threadIdx.x & 63;
    int b = lane & 15, e = lane >> 4;
    float c = bfc[0];
#pragma unroll
    for (int o = 0; o < 16; o++) c = fmaf(b2[o], Wfc[o], c);
    int beg = __builtin_amdgcn_readfirstlane(offs[n]);
    int end = __builtin_amdgcn_readfirstlane(offs[n + 1]);
    float acc = 0.f;
    for (int i = beg + e; i < end; i += 4) {
        int s = csrc[i];
        acc = fmaf(cnorm[i], y[s * 16 + b], acc);
    }
    acc += __shfl_xor(acc, 16);
    acc += __shfl_xor(acc, 32);
    if (lane < 16) out[b * N + n] = acc + c;
}

extern "C" void kernel_launch(void* const* d_in, const int* in_sizes, int n_in,
                              void* d_out, int out_size, void* d_ws, size_t ws_size,
                              hipStream_t stream)
{
    const float* x    = (const float*)d_in[0];
    const int*   eidx = (const int*)d_in[1];
    const float* ew   = (const float*)d_in[2];
    const float* w_ih = (const float*)d_in[3];
    const float* w_hh = (const float*)d_in[4];
    const float* b_ih = (const float*)d_in[5];
    const float* b_hh = (const float*)d_in[6];
    const float* W1   = (const float*)d_in[7];
    const float* b1   = (const float*)d_in[8];
    const float* W2   = (const float*)d_in[9];
    const float* b2   = (const float*)d_in[10];
    const float* Wfc  = (const float*)d_in[11];
    const float* bfc  = (const float*)d_in[12];

    const int E  = in_sizes[2];
    const int BN = in_sizes[0] / TLEN;   // 160000
    const int N  = NNODES;               // 10000
    const int* esrc = eidx;
    const int* etgt = eidx + E;
    float* out = (float*)d_out;

    char* w = (char*)d_ws;
    auto alloc = [&](size_t bytes) -> char* {
        char* p = w;
        w += (bytes + 255) / 256 * 256;
        return p;
    };
    _Float16* xw1   = (_Float16*)alloc((size_t)BN * 32 * 2);  // [n][16][32] fp16
    float* y        = (float*)alloc((size_t)N * 16 * 4);      // [n][16]
    float* deg      = (float*)alloc((size_t)N * 4);
    float* dinv     = (float*)alloc((size_t)N * 4);
    int*   cnt      = (int*)alloc((size_t)N * 4);
    int*   offs     = (int*)alloc((size_t)(N + 4) * 4);
    int*   cursor   = (int*)alloc((size_t)N * 4);
    int*   csr_src  = (int*)alloc((size_t)(E + N) * 4);
    float* csr_norm = (float*)alloc((size_t)(E + N) * 4);

    hipLaunchKernelGGL(init_deg_cnt, dim3((N + 255) / 256), dim3(256), 0, stream, deg, cnt, N);
    hipLaunchKernelGGL(deg_accum, dim3((E + 255) / 256), dim3(256), 0, stream, esrc, etgt, ew, deg, cnt, E);
    hipLaunchKernelGGL(scan_kernel, dim3(1), dim3(1024), 0, stream, cnt, deg, dinv, offs, cursor, N);
    hipLaunchKernelGGL(fill_csr, dim3((E + N + 255) / 256), dim3(256), 0, stream,
                       esrc, etgt, ew, dinv, cursor, csr_src, csr_norm, E, N);

    hipLaunchKernelGGL(gru_xw1_kernel, dim3((BN + 63) / 64), dim3(256), 0, stream,
                       x, w_ih, w_hh, b_ih, b_hh, W1, xw1, BN);
    hipLaunchKernelGGL(conv1y_kernel, dim3((N + 3) / 4), dim3(256), 0, stream,
                       xw1, offs, csr_src, csr_norm, b1, W2, Wfc, y, N);
    hipLaunchKernelGGL(conv2out_kernel, dim3((N + 3) / 4), dim3(256), 0, stream,
                       y, offs, csr_src, csr_norm, b2, Wfc, bfc, out, N);
}